// Round 5
// baseline (207.350 us; speedup 1.0000x reference)
//
#include <hip/hip_runtime.h>
#include <math.h>

// Problem constants (fixed by setup_inputs)
#define NB     128
#define NNODE  64
#define NTOT   8192
#define DIM    64
#define PSTR   136     // padded k-stride (bf16 elems) for Ptb / w2x rows
#define WS72   72      // padded k-stride for small 64-k weight transposes

typedef __bf16 bf16x8 __attribute__((ext_vector_type(8)));
typedef float  f32x4  __attribute__((ext_vector_type(4)));

__device__ __forceinline__ float frcp(float x) {
    return __builtin_amdgcn_rcpf(x);      // v_rcp_f32, ~1 ulp-ish, fine here
}

__device__ __forceinline__ float silu_f(float x) {
    return x * frcp(1.0f + __expf(-x));
}

__device__ __forceinline__ unsigned short bf16bits(float f) {
    return __builtin_bit_cast(unsigned short, (__bf16)f);
}

__device__ __forceinline__ bf16x8 to_bf16x8(const float* v) {
    bf16x8 o;
    #pragma unroll
    for (int j = 0; j < 8; ++j) o[j] = (__bf16)v[j];
    return o;
}

__device__ __forceinline__ float wsum(float v) {
    #pragma unroll
    for (int m = 1; m < 64; m <<= 1) v += __shfl_xor(v, m, 64);
    return v;
}

// ---------------------------------------------------------------------------
// K0: prep transposed bf16 weights + xnorm. grid 128 x 256.
// ---------------------------------------------------------------------------
__global__ __launch_bounds__(256) void k0_prep(
        const float* __restrict__ kvw2, const float* __restrict__ phxw1,
        const float* __restrict__ X, const float* __restrict__ xw,
        const float* __restrict__ qw1, const float* __restrict__ qw2,
        const float* __restrict__ kvw1,
        const float* __restrict__ phh1, const float* __restrict__ phh2,
        unsigned short* __restrict__ w2x, float* __restrict__ Xn4,
        unsigned short* __restrict__ qw1T, unsigned short* __restrict__ qw2T,
        unsigned short* __restrict__ kvw1T,
        unsigned short* __restrict__ phh1T, unsigned short* __restrict__ phh2T) {
    const int k = blockIdx.x;       // 0..127 : k-index and batch id
    const int T = threadIdx.x;
    if (T < 128) {
        w2x[T*PSTR + k] = bf16bits(kvw2[k*128 + T]);
    } else if (T < 192) {
        const int n2 = T - 128;
        float acc = 0.f;
        #pragma unroll 8
        for (int j = 0; j < 64; ++j)
            acc += kvw2[k*128 + 64 + j] * phxw1[j*64 + n2];
        w2x[(128 + n2)*PSTR + k] = bf16bits(acc);
    } else {
        const int L = T - 192;      // wave 3: xnorm for batch k
        const int n = k*64 + L;
        const float x0 = X[n*3+0], x1 = X[n*3+1], x2 = X[n*3+2];
        const float nm = sqrtf(x0*x0 + x1*x1 + x2*x2);
        const float mean = wsum(nm) * (1.0f/64.0f);
        const float sc = xw[0] * frcp(mean + 1e-5f);
        float4 o; o.x = x0*sc; o.y = x1*sc; o.z = x2*sc; o.w = 0.f;
        *(float4*)&Xn4[n*4] = o;
    }
    if (k < 64) {
        if (T < 128) kvw1T[T*WS72 + k] = bf16bits(kvw1[(1+k)*128 + T]);
    } else {
        const int kk = k - 64;
        if (T < 64)       qw1T[T*WS72 + kk]        = bf16bits(qw1[kk*64 + T]);
        else if (T < 128) qw2T[(T-64)*WS72 + kk]   = bf16bits(qw2[kk*64 + (T-64)]);
        else if (T < 192) phh1T[(T-128)*WS72 + kk] = bf16bits(phh1[kk*64 + (T-128)]);
        else              phh2T[(T-192)*WS72 + kk] = bf16bits(phh2[kk*64 + (T-192)]);
    }
}

// ---------------------------------------------------------------------------
// K2 (MFMA): 32-node tiles, 2 waves x 16 rows. grid 256 x 128.
// ---------------------------------------------------------------------------
__global__ __launch_bounds__(128) void k2_node(
        const float* __restrict__ H,
        const unsigned short* __restrict__ qw1T,
        const unsigned short* __restrict__ qw2T,
        const unsigned short* __restrict__ kvw1T,
        const float* __restrict__ qnw, const float* __restrict__ qnb,
        float* __restrict__ Qn, unsigned short* __restrict__ Ptb) {
    const int nb = blockIdx.x * 32;
    const int T = threadIdx.x, w = T >> 6, L = T & 63;
    const int q = L >> 4, m = L & 15;
    __shared__ __align__(16) unsigned short zb[32*WS72];

    bf16x8 hf[2];
    #pragma unroll
    for (int ks = 0; ks < 2; ++ks) {
        float v[8];
        *(float4*)&v[0] = *(const float4*)&H[(size_t)(nb + w*16 + m)*64 + ks*32 + q*8];
        *(float4*)&v[4] = *(const float4*)&H[(size_t)(nb + w*16 + m)*64 + ks*32 + q*8 + 4];
        hf[ks] = to_bf16x8(v);
    }

    // GEMM1: Z = silu(H @ qw1)
    f32x4 acc[4];
    #pragma unroll
    for (int ct = 0; ct < 4; ++ct) acc[ct] = (f32x4){0.f,0.f,0.f,0.f};
    #pragma unroll
    for (int ks = 0; ks < 2; ++ks)
        #pragma unroll
        for (int ct = 0; ct < 4; ++ct) {
            const bf16x8 b = *(const bf16x8*)&qw1T[(ct*16 + m)*WS72 + ks*32 + q*8];
            acc[ct] = __builtin_amdgcn_mfma_f32_16x16x32_bf16(hf[ks], b, acc[ct], 0, 0, 0);
        }
    #pragma unroll
    for (int ct = 0; ct < 4; ++ct)
        #pragma unroll
        for (int r = 0; r < 4; ++r)
            zb[(w*16 + q*4 + r)*WS72 + ct*16 + m] = bf16bits(silu_f(acc[ct][r]));
    __syncthreads();

    // GEMM2: Z2 = Zs @ qw2, then LN
    bf16x8 zf[2];
    #pragma unroll
    for (int ks = 0; ks < 2; ++ks)
        zf[ks] = *(const bf16x8*)&zb[(w*16 + m)*WS72 + ks*32 + q*8];
    #pragma unroll
    for (int ct = 0; ct < 4; ++ct) acc[ct] = (f32x4){0.f,0.f,0.f,0.f};
    #pragma unroll
    for (int ks = 0; ks < 2; ++ks)
        #pragma unroll
        for (int ct = 0; ct < 4; ++ct) {
            const bf16x8 b = *(const bf16x8*)&qw2T[(ct*16 + m)*WS72 + ks*32 + q*8];
            acc[ct] = __builtin_amdgcn_mfma_f32_16x16x32_bf16(zf[ks], b, acc[ct], 0, 0, 0);
        }
    float qnwv[4], qnbv[4];
    #pragma unroll
    for (int ct = 0; ct < 4; ++ct) { qnwv[ct] = qnw[ct*16+m]; qnbv[ct] = qnb[ct*16+m]; }
    #pragma unroll
    for (int r = 0; r < 4; ++r) {
        float s1 = 0.f, s2 = 0.f;
        #pragma unroll
        for (int ct = 0; ct < 4; ++ct) {
            const float z = acc[ct][r];
            s1 += z; s2 = fmaf(z, z, s2);
        }
        #pragma unroll
        for (int sh = 1; sh < 16; sh <<= 1) {
            s1 += __shfl_xor(s1, sh, 64);
            s2 += __shfl_xor(s2, sh, 64);
        }
        const float mu = s1 * (1.0f/64.0f);
        const float rstd = rsqrtf(s2 * (1.0f/64.0f) - mu*mu + 1e-5f);
        const int row = nb + w*16 + q*4 + r;
        #pragma unroll
        for (int ct = 0; ct < 4; ++ct)
            Qn[(size_t)row*64 + ct*16 + m] = (acc[ct][r] - mu)*rstd*qnwv[ct] + qnbv[ct];
    }

    // GEMM3: P = H @ kvw1[1:], two 64-col halves
    #pragma unroll
    for (int ph = 0; ph < 2; ++ph) {
        #pragma unroll
        for (int ct = 0; ct < 4; ++ct) acc[ct] = (f32x4){0.f,0.f,0.f,0.f};
        #pragma unroll
        for (int ks = 0; ks < 2; ++ks)
            #pragma unroll
            for (int ct = 0; ct < 4; ++ct) {
                const bf16x8 b = *(const bf16x8*)&kvw1T[(ph*64 + ct*16 + m)*WS72 + ks*32 + q*8];
                acc[ct] = __builtin_amdgcn_mfma_f32_16x16x32_bf16(hf[ks], b, acc[ct], 0, 0, 0);
            }
        #pragma unroll
        for (int ct = 0; ct < 4; ++ct)
            #pragma unroll
            for (int r = 0; r < 4; ++r)
                Ptb[(size_t)(nb + w*16 + q*4 + r)*PSTR + ph*64 + ct*16 + m]
                    = bf16bits(acc[ct][r]);
    }
}

// ---------------------------------------------------------------------------
// K3: fused edge pipeline. Block = (graph, 16 dsts), 512 thr / 8 waves;
// each wave owns 2 dsts serially. P A-frags read from global (L1/L2-hot);
// weights in LDS. 67 KB LDS -> 2 blocks/CU = 4 waves/SIMD.
// ---------------------------------------------------------------------------
__global__ __launch_bounds__(512, 4) void k3_edge(
        const float* __restrict__ Xn4, const float* __restrict__ Qn,
        const unsigned short* __restrict__ Ptb,
        const unsigned short* __restrict__ w2x,
        const float* __restrict__ kvw1,
        const float* __restrict__ knw, const float* __restrict__ knb,
        const float* __restrict__ pxw2,
        float* __restrict__ Abuf, float* __restrict__ Xout) {
    const int bid = blockIdx.x;
    const int g = bid >> 2, dgrp = bid & 3;
    const int T = threadIdx.x, w = T >> 6, L = T & 63;
    const int q = L >> 4, m = L & 15;

    __shared__ __align__(16) unsigned short sw2[192*PSTR];  // 52224 B
    __shared__ __align__(16) float sXn[64][4];              // 1024 B
    __shared__ __align__(16) float sQn[16][64];             // 4096 B
    __shared__ __align__(16) float xrw[8][64][4];           // 8192 B
    __shared__ float w0s[128];                              // 512 B
    __shared__ float knws[64], knbs[64], pxs[64];           // 768 B

    // ---- staging (once per block) ----
    {
        const uint4* s1 = (const uint4*)w2x;
        uint4* d1 = (uint4*)sw2;
        for (int idx = T; idx < 192*PSTR/8; idx += 512) d1[idx] = s1[idx];
        const float* qsrc = Qn + ((size_t)g*64 + dgrp*16)*64;
        for (int idx = T; idx < 1024; idx += 512)
            sQn[idx >> 6][idx & 63] = qsrc[idx];
        if (T < 64) *(float4*)&sXn[T][0] = *(const float4*)&Xn4[(g*64 + T)*4];
        if (T < 128) w0s[T] = kvw1[T];
        if (T < 64)            knws[T]       = knw[T];
        else if (T < 128)      knbs[T - 64]  = knb[T - 64];
        else if (T < 192)      pxs[T - 128]  = pxw2[T - 128];
    }
    __syncthreads();

    const unsigned short* PtG = Ptb + (size_t)g*64*PSTR;

    #pragma unroll 1
    for (int i = 0; i < 2; ++i) {
        const int dql = i*8 + w;            // 0..15 local dst
        const int dl  = dgrp*16 + dql;      // 0..63 in-graph dst
        const int d   = g*64 + dl;

        // ---- per-src geometry -> xrw[w][s] = {xr0,xr1,xr2,rd} ----
        asm volatile("s_waitcnt lgkmcnt(0)" ::: "memory");
        {
            const float4 xs  = *(const float4*)&sXn[L][0];
            const float4 xdv = *(const float4*)&sXn[dl][0];
            const float r0 = xs.x - xdv.x, r1 = xs.y - xdv.y, r2 = xs.z - xdv.z;
            const float rd = r0*r0 + r1*r1 + r2*r2;
            const float inv = frcp(1.0f + sqrtf(rd + 1e-8f));
            float4 o; o.x = r0*inv; o.y = r1*inv; o.z = r2*inv; o.w = rd;
            *(float4*)&xrw[w][L][0] = o;
        }
        asm volatile("s_waitcnt lgkmcnt(0)" ::: "memory");

        // ---- build t A-fragments in registers (P from global, L1/L2-hot) ----
        bf16x8 af[4][4];
        float rdv[4];
        #pragma unroll
        for (int rt = 0; rt < 4; ++rt) rdv[rt] = xrw[w][rt*16 + m][3];
        #pragma unroll
        for (int ks = 0; ks < 4; ++ks) {
            float w0v[8];
            *(float4*)&w0v[0] = *(const float4*)&w0s[ks*32 + q*8];
            *(float4*)&w0v[4] = *(const float4*)&w0s[ks*32 + q*8 + 4];
            #pragma unroll
            for (int rt = 0; rt < 4; ++rt) {
                const bf16x8 pb = *(const bf16x8*)&PtG[(size_t)(rt*16 + m)*PSTR + ks*32 + q*8];
                bf16x8 o;
                #pragma unroll
                for (int j = 0; j < 8; ++j) {
                    const float pf = (float)pb[j];
                    o[j] = (__bf16)silu_f(fmaf(rdv[rt], w0v[j], pf));
                }
                af[rt][ks] = o;
            }
        }

        f32x4 acc[4][4];

        // ---- K-pass: cols 0..63 ----
        #pragma unroll
        for (int ct = 0; ct < 4; ++ct)
            #pragma unroll
            for (int rt = 0; rt < 4; ++rt)
                acc[ct][rt] = (f32x4){0.f, 0.f, 0.f, 0.f};
        #pragma unroll
        for (int ks = 0; ks < 4; ++ks)
            #pragma unroll
            for (int ct = 0; ct < 4; ++ct) {
                const bf16x8 b = *(const bf16x8*)&sw2[(ct*16 + m)*PSTR + ks*32 + q*8];
                #pragma unroll
                for (int rt = 0; rt < 4; ++rt)
                    acc[ct][rt] = __builtin_amdgcn_mfma_f32_16x16x32_bf16(
                                      af[rt][ks], b, acc[ct][rt], 0, 0, 0);
            }

        // ---- LN(K)+score from C-frags ----
        float qdw[4], Sqdw = 0.f, Sqdb = 0.f;
        #pragma unroll
        for (int ct = 0; ct < 4; ++ct) {
            const float qd = sQn[dql][ct*16 + m];
            qdw[ct] = qd * knws[ct*16 + m];
            Sqdw += qdw[ct];
            Sqdb += qd * knbs[ct*16 + m];
        }
        #pragma unroll
        for (int sh = 1; sh < 16; sh <<= 1) {
            Sqdw += __shfl_xor(Sqdw, sh, 64);
            Sqdb += __shfl_xor(Sqdb, sh, 64);
        }
        float sc[4][4];
        #pragma unroll
        for (int rt = 0; rt < 4; ++rt)
            #pragma unroll
            for (int r = 0; r < 4; ++r) {
                float s1 = 0.f, s2 = 0.f, skq = 0.f;
                #pragma unroll
                for (int ct = 0; ct < 4; ++ct) {
                    const float kv = acc[ct][rt][r];
                    s1 += kv; s2 = fmaf(kv, kv, s2); skq = fmaf(kv, qdw[ct], skq);
                }
                #pragma unroll
                for (int sh = 1; sh < 16; sh <<= 1) {
                    s1  += __shfl_xor(s1,  sh, 64);
                    s2  += __shfl_xor(s2,  sh, 64);
                    skq += __shfl_xor(skq, sh, 64);
                }
                const float mu = s1 * (1.0f/64.0f);
                const float rstd = rsqrtf(s2 * (1.0f/64.0f) - mu*mu + 1e-5f);
                const float scv = (rstd * (skq - mu*Sqdw) + Sqdb) * 0.125f;
                const int row = rt*16 + q*4 + r;
                sc[rt][r] = (row == dl) ? -1e30f : scv;
            }

        // ---- softmax ----
        float mx = -1e30f;
        #pragma unroll
        for (int rt = 0; rt < 4; ++rt)
            #pragma unroll
            for (int r = 0; r < 4; ++r) mx = fmaxf(mx, sc[rt][r]);
        mx = fmaxf(mx, __shfl_xor(mx, 16, 64));
        mx = fmaxf(mx, __shfl_xor(mx, 32, 64));
        float al[4][4], S = 0.f;
        #pragma unroll
        for (int rt = 0; rt < 4; ++rt)
            #pragma unroll
            for (int r = 0; r < 4; ++r) {
                al[rt][r] = __expf(sc[rt][r] - mx);
                S += al[rt][r];
            }
        S += __shfl_xor(S, 16, 64);
        S += __shfl_xor(S, 32, 64);
        const float rS = frcp(S);
        #pragma unroll
        for (int rt = 0; rt < 4; ++rt)
            #pragma unroll
            for (int r = 0; r < 4; ++r) al[rt][r] *= rS;

        // ---- V-pass: cols 64..127 ----
        #pragma unroll
        for (int ct = 0; ct < 4; ++ct)
            #pragma unroll
            for (int rt = 0; rt < 4; ++rt)
                acc[ct][rt] = (f32x4){0.f, 0.f, 0.f, 0.f};
        #pragma unroll
        for (int ks = 0; ks < 4; ++ks)
            #pragma unroll
            for (int ct = 0; ct < 4; ++ct) {
                const bf16x8 b = *(const bf16x8*)&sw2[(64 + ct*16 + m)*PSTR + ks*32 + q*8];
                #pragma unroll
                for (int rt = 0; rt < 4; ++rt)
                    acc[ct][rt] = __builtin_amdgcn_mfma_f32_16x16x32_bf16(
                                      af[rt][ks], b, acc[ct][rt], 0, 0, 0);
            }
        #pragma unroll
        for (int ct = 0; ct < 4; ++ct) {
            float p = 0.f;
            #pragma unroll
            for (int rt = 0; rt < 4; ++rt)
                #pragma unroll
                for (int r = 0; r < 4; ++r)
                    p = fmaf(al[rt][r], acc[ct][rt][r], p);
            p += __shfl_xor(p, 16, 64);
            p += __shfl_xor(p, 32, 64);
            if (q == 0) Abuf[(size_t)d*64 + ct*16 + m] = p;
        }

        // ---- G-pass: cols 128..191 ----
        #pragma unroll
        for (int ct = 0; ct < 4; ++ct)
            #pragma unroll
            for (int rt = 0; rt < 4; ++rt)
                acc[ct][rt] = (f32x4){0.f, 0.f, 0.f, 0.f};
        #pragma unroll
        for (int ks = 0; ks < 4; ++ks)
            #pragma unroll
            for (int ct = 0; ct < 4; ++ct) {
                const bf16x8 b = *(const bf16x8*)&sw2[(128 + ct*16 + m)*PSTR + ks*32 + q*8];
                #pragma unroll
                for (int rt = 0; rt < 4; ++rt)
                    acc[ct][rt] = __builtin_amdgcn_mfma_f32_16x16x32_bf16(
                                      af[rt][ks], b, acc[ct][rt], 0, 0, 0);
            }

        // ---- phx epilogue + X accumulation ----
        float pxc[4];
        #pragma unroll
        for (int ct = 0; ct < 4; ++ct) pxc[ct] = pxs[ct*16 + m];
        float xa0 = 0.f, xa1 = 0.f, xa2 = 0.f;
        #pragma unroll
        for (int rt = 0; rt < 4; ++rt)
            #pragma unroll
            for (int r = 0; r < 4; ++r) {
                float ph = 0.f;
                #pragma unroll
                for (int ct = 0; ct < 4; ++ct)
                    ph = fmaf(silu_f(al[rt][r] * acc[ct][rt][r]), pxc[ct], ph);
                #pragma unroll
                for (int sh = 1; sh < 16; sh <<= 1) ph += __shfl_xor(ph, sh, 64);
                const float4 xr = *(const float4*)&xrw[w][rt*16 + q*4 + r][0];
                xa0 = fmaf(ph, xr.x, xa0);
                xa1 = fmaf(ph, xr.y, xa1);
                xa2 = fmaf(ph, xr.z, xa2);
            }
        xa0 += __shfl_xor(xa0, 16, 64); xa0 += __shfl_xor(xa0, 32, 64);
        xa1 += __shfl_xor(xa1, 16, 64); xa1 += __shfl_xor(xa1, 32, 64);
        xa2 += __shfl_xor(xa2, 16, 64); xa2 += __shfl_xor(xa2, 32, 64);
        if (L == 0) {
            const float4 xdv = *(const float4*)&sXn[dl][0];
            Xout[(size_t)d*3 + 0] = xdv.x + xa0;
            Xout[(size_t)d*3 + 1] = xdv.y + xa1;
            Xout[(size_t)d*3 + 2] = xdv.z + xa2;
        }
    }
}

// ---------------------------------------------------------------------------
// K4 (MFMA): H_out = H + silu((A*A*H)@phh1 + b1)@phh2 + b2, 32-node tiles.
// ---------------------------------------------------------------------------
__global__ __launch_bounds__(128) void k4_hout(
        const float* __restrict__ H, const float* __restrict__ Abuf,
        const unsigned short* __restrict__ phh1T, const float* __restrict__ b1,
        const unsigned short* __restrict__ phh2T, const float* __restrict__ b2,
        float* __restrict__ Hout) {
    const int nb = blockIdx.x * 32;
    const int T = threadIdx.x, w = T >> 6, L = T & 63;
    const int q = L >> 4, m = L & 15;
    __shared__ __align__(16) unsigned short zb[32*WS72];

    bf16x8 uf[2];
    #pragma unroll
    for (int ks = 0; ks < 2; ++ks) {
        const size_t base = (size_t)(nb + w*16 + m)*64 + ks*32 + q*8;
        float a[8], h[8], v[8];
        *(float4*)&a[0] = *(const float4*)&Abuf[base];
        *(float4*)&a[4] = *(const float4*)&Abuf[base + 4];
        *(float4*)&h[0] = *(const float4*)&H[base];
        *(float4*)&h[4] = *(const float4*)&H[base + 4];
        #pragma unroll
        for (int j = 0; j < 8; ++j) v[j] = a[j]*a[j]*h[j];
        uf[ks] = to_bf16x8(v);
    }

    f32x4 acc[4];
    #pragma unroll
    for (int ct = 0; ct < 4; ++ct) acc[ct] = (f32x4){0.f,0.f,0.f,0.f};
    #pragma unroll
    for (int ks = 0; ks < 2; ++ks)
        #pragma unroll
        for (int ct = 0; ct < 4; ++ct) {
            const bf16x8 b = *(const bf16x8*)&phh1T[(ct*16 + m)*WS72 + ks*32 + q*8];
            acc[ct] = __builtin_amdgcn_mfma_f32_16x16x32_bf16(uf[ks], b, acc[ct], 0, 0, 0);
        }
    #pragma unroll
    for (int ct = 0; ct < 4; ++ct) {
        const float bv = b1[ct*16 + m];
        #pragma unroll
        for (int r = 0; r < 4; ++r)
            zb[(w*16 + q*4 + r)*WS72 + ct*16 + m] = bf16bits(silu_f(acc[ct][r] + bv));
    }
    __syncthreads();

    bf16x8 zf[2];
    #pragma unroll
    for (int ks = 0; ks < 2; ++ks)
        zf[ks] = *(const bf16x8*)&zb[(w*16 + m)*WS72 + ks*32 + q*8];
    #pragma unroll
    for (int ct = 0; ct < 4; ++ct) acc[ct] = (f32x4){0.f,0.f,0.f,0.f};
    #pragma unroll
    for (int ks = 0; ks < 2; ++ks)
        #pragma unroll
        for (int ct = 0; ct < 4; ++ct) {
            const bf16x8 b = *(const bf16x8*)&phh2T[(ct*16 + m)*WS72 + ks*32 + q*8];
            acc[ct] = __builtin_amdgcn_mfma_f32_16x16x32_bf16(zf[ks], b, acc[ct], 0, 0, 0);
        }
    #pragma unroll
    for (int ct = 0; ct < 4; ++ct) {
        const float bv = b2[ct*16 + m];
        #pragma unroll
        for (int r = 0; r < 4; ++r) {
            const size_t idx = (size_t)(nb + w*16 + q*4 + r)*64 + ct*16 + m;
            Hout[idx] = H[idx] + acc[ct][r] + bv;
        }
    }
}

// ---------------------------------------------------------------------------
extern "C" void kernel_launch(void* const* d_in, const int* in_sizes, int n_in,
                              void* d_out, int out_size, void* d_ws, size_t ws_size,
                              hipStream_t stream) {
    const float* X    = (const float*)d_in[1];
    const float* H    = (const float*)d_in[2];
    const float* xw   = (const float*)d_in[4];
    const float* qw1  = (const float*)d_in[5];
    const float* qw2  = (const float*)d_in[6];
    const float* kvw1 = (const float*)d_in[7];
    const float* kvw2 = (const float*)d_in[8];
    const float* qnw  = (const float*)d_in[9];
    const float* qnb  = (const float*)d_in[10];
    const float* knw  = (const float*)d_in[11];
    const float* knb  = (const float*)d_in[12];
    const float* pxw1 = (const float*)d_in[13];
    const float* pxw2 = (const float*)d_in[14];
    const float* phw1 = (const float*)d_in[15];
    const float* phb1 = (const float*)d_in[16];
    const float* phw2 = (const float*)d_in[17];
    const float* phb2 = (const float*)d_in[18];

    float* out = (float*)d_out;
    char*  ws  = (char*)d_ws;

    size_t off = 0;
    float* Xn4 = (float*)(ws + off);          off += (size_t)NTOT*4*4;
    float* Qn  = (float*)(ws + off);          off += (size_t)NTOT*64*4;
    unsigned short* Ptb = (unsigned short*)(ws + off); off += (size_t)NTOT*PSTR*2;
    float* Ab  = (float*)(ws + off);          off += (size_t)NTOT*64*4;
    unsigned short* w2x   = (unsigned short*)(ws + off); off += (size_t)192*PSTR*2;
    unsigned short* qw1T  = (unsigned short*)(ws + off); off += (size_t)64*WS72*2;
    unsigned short* qw2T  = (unsigned short*)(ws + off); off += (size_t)64*WS72*2;
    unsigned short* kvw1T = (unsigned short*)(ws + off); off += (size_t)128*WS72*2;
    unsigned short* phh1T = (unsigned short*)(ws + off); off += (size_t)64*WS72*2;
    unsigned short* phh2T = (unsigned short*)(ws + off); off += (size_t)64*WS72*2;

    k0_prep<<<128, 256, 0, stream>>>(kvw2, pxw1, X, xw, qw1, qw2, kvw1,
                                     phw1, phw2, w2x, Xn4,
                                     qw1T, qw2T, kvw1T, phh1T, phh2T);
    k2_node<<<256, 128, 0, stream>>>(H, qw1T, qw2T, kvw1T, qnw, qnb, Qn, Ptb);
    k3_edge<<<512, 512, 0, stream>>>(Xn4, Qn, Ptb, w2x, kvw1, knw, knb,
                                     pxw2, Ab, out);
    k4_hout<<<256, 128, 0, stream>>>(H, Ab, phh1T, phb1, phh2T, phb2,
                                     out + NTOT*3);
}

// Round 6
// 196.725 us; speedup vs baseline: 1.0540x; 1.0540x over previous
//
#include <hip/hip_runtime.h>
#include <math.h>

// Problem constants (fixed by setup_inputs)
#define NB     128
#define NNODE  64
#define NTOT   8192
#define DIM    64
#define PSTR   136     // padded k-stride (bf16 elems) for Ptb / w2x rows
#define WS72   72      // padded k-stride for small 64-k weight transposes

typedef __bf16 bf16x8 __attribute__((ext_vector_type(8)));
typedef float  f32x4  __attribute__((ext_vector_type(4)));

__device__ __forceinline__ float frcp(float x) {
    return __builtin_amdgcn_rcpf(x);
}

__device__ __forceinline__ float silu_f(float x) {
    return x * frcp(1.0f + __expf(-x));
}

__device__ __forceinline__ unsigned short bf16bits(float f) {
    return __builtin_bit_cast(unsigned short, (__bf16)f);
}

__device__ __forceinline__ bf16x8 to_bf16x8(const float* v) {
    bf16x8 o;
    #pragma unroll
    for (int j = 0; j < 8; ++j) o[j] = (__bf16)v[j];
    return o;
}

__device__ __forceinline__ float wsum(float v) {
    #pragma unroll
    for (int m = 1; m < 64; m <<= 1) v += __shfl_xor(v, m, 64);
    return v;
}

// ---------------------------------------------------------------------------
// K0: prep transposed bf16 weights + xnorm. grid 128 x 256.
// ---------------------------------------------------------------------------
__global__ __launch_bounds__(256) void k0_prep(
        const float* __restrict__ kvw2, const float* __restrict__ phxw1,
        const float* __restrict__ X, const float* __restrict__ xw,
        const float* __restrict__ qw1, const float* __restrict__ qw2,
        const float* __restrict__ kvw1,
        const float* __restrict__ phh1, const float* __restrict__ phh2,
        unsigned short* __restrict__ w2x, float* __restrict__ Xn4,
        unsigned short* __restrict__ qw1T, unsigned short* __restrict__ qw2T,
        unsigned short* __restrict__ kvw1T,
        unsigned short* __restrict__ phh1T, unsigned short* __restrict__ phh2T) {
    const int k = blockIdx.x;       // 0..127 : k-index and batch id
    const int T = threadIdx.x;
    if (T < 128) {
        w2x[T*PSTR + k] = bf16bits(kvw2[k*128 + T]);
    } else if (T < 192) {
        const int n2 = T - 128;
        float acc = 0.f;
        #pragma unroll 8
        for (int j = 0; j < 64; ++j)
            acc += kvw2[k*128 + 64 + j] * phxw1[j*64 + n2];
        w2x[(128 + n2)*PSTR + k] = bf16bits(acc);
    } else {
        const int L = T - 192;      // wave 3: xnorm for batch k
        const int n = k*64 + L;
        const float x0 = X[n*3+0], x1 = X[n*3+1], x2 = X[n*3+2];
        const float nm = sqrtf(x0*x0 + x1*x1 + x2*x2);
        const float mean = wsum(nm) * (1.0f/64.0f);
        const float sc = xw[0] * frcp(mean + 1e-5f);
        float4 o; o.x = x0*sc; o.y = x1*sc; o.z = x2*sc; o.w = 0.f;
        *(float4*)&Xn4[n*4] = o;
    }
    if (k < 64) {
        if (T < 128) kvw1T[T*WS72 + k] = bf16bits(kvw1[(1+k)*128 + T]);
    } else {
        const int kk = k - 64;
        if (T < 64)       qw1T[T*WS72 + kk]        = bf16bits(qw1[kk*64 + T]);
        else if (T < 128) qw2T[(T-64)*WS72 + kk]   = bf16bits(qw2[kk*64 + (T-64)]);
        else if (T < 192) phh1T[(T-128)*WS72 + kk] = bf16bits(phh1[kk*64 + (T-128)]);
        else              phh2T[(T-192)*WS72 + kk] = bf16bits(phh2[kk*64 + (T-192)]);
    }
}

// ---------------------------------------------------------------------------
// K2 (MFMA): 32-node tiles, 2 waves x 16 rows. grid 256 x 128.
// ---------------------------------------------------------------------------
__global__ __launch_bounds__(128) void k2_node(
        const float* __restrict__ H,
        const unsigned short* __restrict__ qw1T,
        const unsigned short* __restrict__ qw2T,
        const unsigned short* __restrict__ kvw1T,
        const float* __restrict__ qnw, const float* __restrict__ qnb,
        float* __restrict__ Qn, unsigned short* __restrict__ Ptb) {
    const int nb = blockIdx.x * 32;
    const int T = threadIdx.x, w = T >> 6, L = T & 63;
    const int q = L >> 4, m = L & 15;
    __shared__ __align__(16) unsigned short zb[32*WS72];

    bf16x8 hf[2];
    #pragma unroll
    for (int ks = 0; ks < 2; ++ks) {
        float v[8];
        *(float4*)&v[0] = *(const float4*)&H[(size_t)(nb + w*16 + m)*64 + ks*32 + q*8];
        *(float4*)&v[4] = *(const float4*)&H[(size_t)(nb + w*16 + m)*64 + ks*32 + q*8 + 4];
        hf[ks] = to_bf16x8(v);
    }

    // GEMM1: Z = silu(H @ qw1)
    f32x4 acc[4];
    #pragma unroll
    for (int ct = 0; ct < 4; ++ct) acc[ct] = (f32x4){0.f,0.f,0.f,0.f};
    #pragma unroll
    for (int ks = 0; ks < 2; ++ks)
        #pragma unroll
        for (int ct = 0; ct < 4; ++ct) {
            const bf16x8 b = *(const bf16x8*)&qw1T[(ct*16 + m)*WS72 + ks*32 + q*8];
            acc[ct] = __builtin_amdgcn_mfma_f32_16x16x32_bf16(hf[ks], b, acc[ct], 0, 0, 0);
        }
    #pragma unroll
    for (int ct = 0; ct < 4; ++ct)
        #pragma unroll
        for (int r = 0; r < 4; ++r)
            zb[(w*16 + q*4 + r)*WS72 + ct*16 + m] = bf16bits(silu_f(acc[ct][r]));
    __syncthreads();

    // GEMM2: Z2 = Zs @ qw2, then LN
    bf16x8 zf[2];
    #pragma unroll
    for (int ks = 0; ks < 2; ++ks)
        zf[ks] = *(const bf16x8*)&zb[(w*16 + m)*WS72 + ks*32 + q*8];
    #pragma unroll
    for (int ct = 0; ct < 4; ++ct) acc[ct] = (f32x4){0.f,0.f,0.f,0.f};
    #pragma unroll
    for (int ks = 0; ks < 2; ++ks)
        #pragma unroll
        for (int ct = 0; ct < 4; ++ct) {
            const bf16x8 b = *(const bf16x8*)&qw2T[(ct*16 + m)*WS72 + ks*32 + q*8];
            acc[ct] = __builtin_amdgcn_mfma_f32_16x16x32_bf16(zf[ks], b, acc[ct], 0, 0, 0);
        }
    float qnwv[4], qnbv[4];
    #pragma unroll
    for (int ct = 0; ct < 4; ++ct) { qnwv[ct] = qnw[ct*16+m]; qnbv[ct] = qnb[ct*16+m]; }
    #pragma unroll
    for (int r = 0; r < 4; ++r) {
        float s1 = 0.f, s2 = 0.f;
        #pragma unroll
        for (int ct = 0; ct < 4; ++ct) {
            const float z = acc[ct][r];
            s1 += z; s2 = fmaf(z, z, s2);
        }
        #pragma unroll
        for (int sh = 1; sh < 16; sh <<= 1) {
            s1 += __shfl_xor(s1, sh, 64);
            s2 += __shfl_xor(s2, sh, 64);
        }
        const float mu = s1 * (1.0f/64.0f);
        const float rstd = rsqrtf(s2 * (1.0f/64.0f) - mu*mu + 1e-5f);
        const int row = nb + w*16 + q*4 + r;
        #pragma unroll
        for (int ct = 0; ct < 4; ++ct)
            Qn[(size_t)row*64 + ct*16 + m] = (acc[ct][r] - mu)*rstd*qnwv[ct] + qnbv[ct];
    }

    // GEMM3: P = H @ kvw1[1:], two 64-col halves
    #pragma unroll
    for (int ph = 0; ph < 2; ++ph) {
        #pragma unroll
        for (int ct = 0; ct < 4; ++ct) acc[ct] = (f32x4){0.f,0.f,0.f,0.f};
        #pragma unroll
        for (int ks = 0; ks < 2; ++ks)
            #pragma unroll
            for (int ct = 0; ct < 4; ++ct) {
                const bf16x8 b = *(const bf16x8*)&kvw1T[(ph*64 + ct*16 + m)*WS72 + ks*32 + q*8];
                acc[ct] = __builtin_amdgcn_mfma_f32_16x16x32_bf16(hf[ks], b, acc[ct], 0, 0, 0);
            }
        #pragma unroll
        for (int ct = 0; ct < 4; ++ct)
            #pragma unroll
            for (int r = 0; r < 4; ++r)
                Ptb[(size_t)(nb + w*16 + q*4 + r)*PSTR + ph*64 + ct*16 + m]
                    = bf16bits(acc[ct][r]);
    }
}

// ---------------------------------------------------------------------------
// K3: fused edge pipeline, pair-wave version. Block = (graph, 16 dsts),
// 512 thr / 8 waves / 4 wave-pairs. Pair p handles dsts {i*4+p}, i=0..3;
// within a pair, wave half h owns src rows [32h, 32h+32) (rt-split), so
// t-build / K-LN / score stay wave-local. Cross-wave per dst: softmax
// (max+sum rescale), A col-partials, xa 3-vector — via tiny LDS + 3 barriers.
// Per-wave regs: af[2][4]=32 + acc[4][2]=32(AGPR) + al 8 + temps ≈ 105 < 128
// -> true 4 waves/SIMD with no spill.
// ---------------------------------------------------------------------------
__global__ __launch_bounds__(512, 4) void k3_edge(
        const float* __restrict__ Xn4, const float* __restrict__ Qn,
        const unsigned short* __restrict__ Ptb,
        const unsigned short* __restrict__ w2x,
        const float* __restrict__ kvw1,
        const float* __restrict__ knw, const float* __restrict__ knb,
        const float* __restrict__ pxw2,
        float* __restrict__ Abuf, float* __restrict__ Xout) {
    const int bid = blockIdx.x;
    const int g = bid >> 2, dgrp = bid & 3;
    const int T = threadIdx.x, w = T >> 6, L = T & 63;
    const int q = L >> 4, m = L & 15;
    const int pair = w >> 1, half = w & 1;

    __shared__ __align__(16) unsigned short sw2[192*PSTR];  // 52224 B
    __shared__ __align__(16) float sXn[64][4];              // 1024 B
    __shared__ __align__(16) float sQn[16][64];             // 4096 B
    __shared__ __align__(16) float sxr[8][32][4];           // 4096 B (per-wave)
    __shared__ float w0s[128];                              // 512 B
    __shared__ float knws[64], knbs[64], pxs[64];           // 768 B
    __shared__ float sred[4][2][2];                         // softmax exchange
    __shared__ float sA[4][64];                             // A col partials
    __shared__ float sX[4][4];                              // xa partials

    // ---- staging (once per block) ----
    {
        const uint4* s1 = (const uint4*)w2x;
        uint4* d1 = (uint4*)sw2;
        for (int idx = T; idx < 192*PSTR/8; idx += 512) d1[idx] = s1[idx];
        const float* qsrc = Qn + ((size_t)g*64 + dgrp*16)*64;
        for (int idx = T; idx < 1024; idx += 512)
            sQn[idx >> 6][idx & 63] = qsrc[idx];
        if (T < 64) *(float4*)&sXn[T][0] = *(const float4*)&Xn4[(g*64 + T)*4];
        if (T < 128) w0s[T] = kvw1[T];
        if (T < 64)            knws[T]       = knw[T];
        else if (T < 128)      knbs[T - 64]  = knb[T - 64];
        else if (T < 192)      pxs[T - 128]  = pxw2[T - 128];
    }
    __syncthreads();

    const unsigned short* PtG = Ptb + (size_t)g*64*PSTR;

    #pragma unroll 1
    for (int i = 0; i < 4; ++i) {
        const int dql = i*4 + pair;         // 0..15 local dst
        const int dl  = dgrp*16 + dql;      // 0..63 in-graph dst
        const int d   = g*64 + dl;

        // ---- geometry for this wave's 32 src rows ----
        if (L < 32) {
            const int row = half*32 + L;
            const float4 xs  = *(const float4*)&sXn[row][0];
            const float4 xdv = *(const float4*)&sXn[dl][0];
            const float r0 = xs.x - xdv.x, r1 = xs.y - xdv.y, r2 = xs.z - xdv.z;
            const float rd = r0*r0 + r1*r1 + r2*r2;
            const float inv = frcp(1.0f + sqrtf(rd + 1e-8f));
            float4 o; o.x = r0*inv; o.y = r1*inv; o.z = r2*inv; o.w = rd;
            *(float4*)&sxr[w][L][0] = o;
        }

        // ---- build t A-fragments (rows half*32 + rt*16 + m) ----
        bf16x8 af[2][4];
        float rdv[2];
        #pragma unroll
        for (int rt = 0; rt < 2; ++rt) rdv[rt] = sxr[w][rt*16 + m][3];
        #pragma unroll
        for (int ks = 0; ks < 4; ++ks) {
            float w0v[8];
            *(float4*)&w0v[0] = *(const float4*)&w0s[ks*32 + q*8];
            *(float4*)&w0v[4] = *(const float4*)&w0s[ks*32 + q*8 + 4];
            #pragma unroll
            for (int rt = 0; rt < 2; ++rt) {
                const int row = half*32 + rt*16 + m;
                const bf16x8 pb = *(const bf16x8*)&PtG[(size_t)row*PSTR + ks*32 + q*8];
                bf16x8 o;
                #pragma unroll
                for (int j = 0; j < 8; ++j) {
                    const float pf = (float)pb[j];
                    o[j] = (__bf16)silu_f(fmaf(rdv[rt], w0v[j], pf));
                }
                af[rt][ks] = o;
            }
        }

        f32x4 acc[4][2];

        // ---- K-pass: cols 0..63 ----
        #pragma unroll
        for (int ct = 0; ct < 4; ++ct)
            #pragma unroll
            for (int rt = 0; rt < 2; ++rt)
                acc[ct][rt] = (f32x4){0.f, 0.f, 0.f, 0.f};
        #pragma unroll
        for (int ks = 0; ks < 4; ++ks)
            #pragma unroll
            for (int ct = 0; ct < 4; ++ct) {
                const bf16x8 b = *(const bf16x8*)&sw2[(ct*16 + m)*PSTR + ks*32 + q*8];
                #pragma unroll
                for (int rt = 0; rt < 2; ++rt)
                    acc[ct][rt] = __builtin_amdgcn_mfma_f32_16x16x32_bf16(
                                      af[rt][ks], b, acc[ct][rt], 0, 0, 0);
            }

        // ---- LN(K)+score from C-frags (rows of this wave only) ----
        float qdw[4], Sqdw = 0.f, Sqdb = 0.f;
        #pragma unroll
        for (int ct = 0; ct < 4; ++ct) {
            const float qd = sQn[dql][ct*16 + m];
            qdw[ct] = qd * knws[ct*16 + m];
            Sqdw += qdw[ct];
            Sqdb += qd * knbs[ct*16 + m];
        }
        #pragma unroll
        for (int sh = 1; sh < 16; sh <<= 1) {
            Sqdw += __shfl_xor(Sqdw, sh, 64);
            Sqdb += __shfl_xor(Sqdb, sh, 64);
        }
        float sc[2][4];
        #pragma unroll
        for (int rt = 0; rt < 2; ++rt)
            #pragma unroll
            for (int r = 0; r < 4; ++r) {
                float s1 = 0.f, s2 = 0.f, skq = 0.f;
                #pragma unroll
                for (int ct = 0; ct < 4; ++ct) {
                    const float kv = acc[ct][rt][r];
                    s1 += kv; s2 = fmaf(kv, kv, s2); skq = fmaf(kv, qdw[ct], skq);
                }
                #pragma unroll
                for (int sh = 1; sh < 16; sh <<= 1) {
                    s1  += __shfl_xor(s1,  sh, 64);
                    s2  += __shfl_xor(s2,  sh, 64);
                    skq += __shfl_xor(skq, sh, 64);
                }
                const float mu = s1 * (1.0f/64.0f);
                const float rstd = rsqrtf(s2 * (1.0f/64.0f) - mu*mu + 1e-5f);
                const float scv = (rstd * (skq - mu*Sqdw) + Sqdb) * 0.125f;
                const int row_g = half*32 + rt*16 + q*4 + r;
                sc[rt][r] = (row_g == dl) ? -1e30f : scv;
            }

        // ---- softmax: wave-local partial, cross-wave rescale merge ----
        float mx = -1e30f;
        #pragma unroll
        for (int rt = 0; rt < 2; ++rt)
            #pragma unroll
            for (int r = 0; r < 4; ++r) mx = fmaxf(mx, sc[rt][r]);
        mx = fmaxf(mx, __shfl_xor(mx, 16, 64));
        mx = fmaxf(mx, __shfl_xor(mx, 32, 64));
        float al[2][4], S = 0.f;
        #pragma unroll
        for (int rt = 0; rt < 2; ++rt)
            #pragma unroll
            for (int r = 0; r < 4; ++r) {
                al[rt][r] = __expf(sc[rt][r] - mx);
                S += al[rt][r];
            }
        S += __shfl_xor(S, 16, 64);
        S += __shfl_xor(S, 32, 64);
        S *= 0.25f;                     // each row counted by 4 q-groups? no:
        // rows split by q; the shfl over 16/32 sums the 4 q-groups, each of
        // which holds DIFFERENT rows, but every m-lane in a q-group holds the
        // SAME row set -> after q-sum, S is the true row-sum (m-replicated).
        S *= 4.0f;                      // undo the guard above (kept explicit)
        if (L == 0) { sred[pair][half][0] = mx; sred[pair][half][1] = S; }
        __syncthreads();                                    // b1
        {
            const float mo = sred[pair][half^1][0];
            const float So = sred[pair][half^1][1];
            const float M  = fmaxf(mx, mo);
            const float es = __expf(mx - M);
            const float eo = __expf(mo - M);
            const float alf = es * frcp(S*es + So*eo);
            #pragma unroll
            for (int rt = 0; rt < 2; ++rt)
                #pragma unroll
                for (int r = 0; r < 4; ++r) al[rt][r] *= alf;
        }

        // ---- V-pass: cols 64..127 ----
        #pragma unroll
        for (int ct = 0; ct < 4; ++ct)
            #pragma unroll
            for (int rt = 0; rt < 2; ++rt)
                acc[ct][rt] = (f32x4){0.f, 0.f, 0.f, 0.f};
        #pragma unroll
        for (int ks = 0; ks < 4; ++ks)
            #pragma unroll
            for (int ct = 0; ct < 4; ++ct) {
                const bf16x8 b = *(const bf16x8*)&sw2[(64 + ct*16 + m)*PSTR + ks*32 + q*8];
                #pragma unroll
                for (int rt = 0; rt < 2; ++rt)
                    acc[ct][rt] = __builtin_amdgcn_mfma_f32_16x16x32_bf16(
                                      af[rt][ks], b, acc[ct][rt], 0, 0, 0);
            }
        float p[4];
        #pragma unroll
        for (int ct = 0; ct < 4; ++ct) {
            float pv = 0.f;
            #pragma unroll
            for (int rt = 0; rt < 2; ++rt)
                #pragma unroll
                for (int r = 0; r < 4; ++r)
                    pv = fmaf(al[rt][r], acc[ct][rt][r], pv);
            pv += __shfl_xor(pv, 16, 64);
            pv += __shfl_xor(pv, 32, 64);
            p[ct] = pv;
        }
        if (half == 1 && q == 0)
            #pragma unroll
            for (int ct = 0; ct < 4; ++ct) sA[pair][ct*16 + m] = p[ct];
        __syncthreads();                                    // b2
        if (half == 0 && q == 0)
            #pragma unroll
            for (int ct = 0; ct < 4; ++ct)
                Abuf[(size_t)d*64 + ct*16 + m] = p[ct] + sA[pair][ct*16 + m];

        // ---- G-pass: cols 128..191 ----
        #pragma unroll
        for (int ct = 0; ct < 4; ++ct)
            #pragma unroll
            for (int rt = 0; rt < 2; ++rt)
                acc[ct][rt] = (f32x4){0.f, 0.f, 0.f, 0.f};
        #pragma unroll
        for (int ks = 0; ks < 4; ++ks)
            #pragma unroll
            for (int ct = 0; ct < 4; ++ct) {
                const bf16x8 b = *(const bf16x8*)&sw2[(128 + ct*16 + m)*PSTR + ks*32 + q*8];
                #pragma unroll
                for (int rt = 0; rt < 2; ++rt)
                    acc[ct][rt] = __builtin_amdgcn_mfma_f32_16x16x32_bf16(
                                      af[rt][ks], b, acc[ct][rt], 0, 0, 0);
            }

        // ---- phx epilogue + X partial over this wave's 32 rows ----
        float pxc[4];
        #pragma unroll
        for (int ct = 0; ct < 4; ++ct) pxc[ct] = pxs[ct*16 + m];
        float xa0 = 0.f, xa1 = 0.f, xa2 = 0.f;
        #pragma unroll
        for (int rt = 0; rt < 2; ++rt)
            #pragma unroll
            for (int r = 0; r < 4; ++r) {
                float ph = 0.f;
                #pragma unroll
                for (int ct = 0; ct < 4; ++ct)
                    ph = fmaf(silu_f(al[rt][r] * acc[ct][rt][r]), pxc[ct], ph);
                #pragma unroll
                for (int sh = 1; sh < 16; sh <<= 1) ph += __shfl_xor(ph, sh, 64);
                const float4 xr = *(const float4*)&sxr[w][rt*16 + q*4 + r][0];
                xa0 = fmaf(ph, xr.x, xa0);
                xa1 = fmaf(ph, xr.y, xa1);
                xa2 = fmaf(ph, xr.z, xa2);
            }
        xa0 += __shfl_xor(xa0, 16, 64); xa0 += __shfl_xor(xa0, 32, 64);
        xa1 += __shfl_xor(xa1, 16, 64); xa1 += __shfl_xor(xa1, 32, 64);
        xa2 += __shfl_xor(xa2, 16, 64); xa2 += __shfl_xor(xa2, 32, 64);
        if (half == 1 && L == 0) {
            sX[pair][0] = xa0; sX[pair][1] = xa1; sX[pair][2] = xa2;
        }
        __syncthreads();                                    // b3
        if (half == 0 && L == 0) {
            const float4 xdv = *(const float4*)&sXn[dl][0];
            Xout[(size_t)d*3 + 0] = xdv.x + xa0 + sX[pair][0];
            Xout[(size_t)d*3 + 1] = xdv.y + xa1 + sX[pair][1];
            Xout[(size_t)d*3 + 2] = xdv.z + xa2 + sX[pair][2];
        }
    }
}

// ---------------------------------------------------------------------------
// K4 (MFMA): H_out = H + silu((A*A*H)@phh1 + b1)@phh2 + b2, 32-node tiles.
// ---------------------------------------------------------------------------
__global__ __launch_bounds__(128) void k4_hout(
        const float* __restrict__ H, const float* __restrict__ Abuf,
        const unsigned short* __restrict__ phh1T, const float* __restrict__ b1,
        const unsigned short* __restrict__ phh2T, const float* __restrict__ b2,
        float* __restrict__ Hout) {
    const int nb = blockIdx.x * 32;
    const int T = threadIdx.x, w = T >> 6, L = T & 63;
    const int q = L >> 4, m = L & 15;
    __shared__ __align__(16) unsigned short zb[32*WS72];

    bf16x8 uf[2];
    #pragma unroll
    for (int ks = 0; ks < 2; ++ks) {
        const size_t base = (size_t)(nb + w*16 + m)*64 + ks*32 + q*8;
        float a[8], h[8], v[8];
        *(float4*)&a[0] = *(const float4*)&Abuf[base];
        *(float4*)&a[4] = *(const float4*)&Abuf[base + 4];
        *(float4*)&h[0] = *(const float4*)&H[base];
        *(float4*)&h[4] = *(const float4*)&H[base + 4];
        #pragma unroll
        for (int j = 0; j < 8; ++j) v[j] = a[j]*a[j]*h[j];
        uf[ks] = to_bf16x8(v);
    }

    f32x4 acc[4];
    #pragma unroll
    for (int ct = 0; ct < 4; ++ct) acc[ct] = (f32x4){0.f,0.f,0.f,0.f};
    #pragma unroll
    for (int ks = 0; ks < 2; ++ks)
        #pragma unroll
        for (int ct = 0; ct < 4; ++ct) {
            const bf16x8 b = *(const bf16x8*)&phh1T[(ct*16 + m)*WS72 + ks*32 + q*8];
            acc[ct] = __builtin_amdgcn_mfma_f32_16x16x32_bf16(uf[ks], b, acc[ct], 0, 0, 0);
        }
    #pragma unroll
    for (int ct = 0; ct < 4; ++ct) {
        const float bv = b1[ct*16 + m];
        #pragma unroll
        for (int r = 0; r < 4; ++r)
            zb[(w*16 + q*4 + r)*WS72 + ct*16 + m] = bf16bits(silu_f(acc[ct][r] + bv));
    }
    __syncthreads();

    bf16x8 zf[2];
    #pragma unroll
    for (int ks = 0; ks < 2; ++ks)
        zf[ks] = *(const bf16x8*)&zb[(w*16 + m)*WS72 + ks*32 + q*8];
    #pragma unroll
    for (int ct = 0; ct < 4; ++ct) acc[ct] = (f32x4){0.f,0.f,0.f,0.f};
    #pragma unroll
    for (int ks = 0; ks < 2; ++ks)
        #pragma unroll
        for (int ct = 0; ct < 4; ++ct) {
            const bf16x8 b = *(const bf16x8*)&phh2T[(ct*16 + m)*WS72 + ks*32 + q*8];
            acc[ct] = __builtin_amdgcn_mfma_f32_16x16x32_bf16(zf[ks], b, acc[ct], 0, 0, 0);
        }
    #pragma unroll
    for (int ct = 0; ct < 4; ++ct) {
        const float bv = b2[ct*16 + m];
        #pragma unroll
        for (int r = 0; r < 4; ++r) {
            const size_t idx = (size_t)(nb + w*16 + q*4 + r)*64 + ct*16 + m;
            Hout[idx] = H[idx] + acc[ct][r] + bv;
        }
    }
}

// ---------------------------------------------------------------------------
extern "C" void kernel_launch(void* const* d_in, const int* in_sizes, int n_in,
                              void* d_out, int out_size, void* d_ws, size_t ws_size,
                              hipStream_t stream) {
    const float* X    = (const float*)d_in[1];
    const float* H    = (const float*)d_in[2];
    const float* xw   = (const float*)d_in[4];
    const float* qw1  = (const float*)d_in[5];
    const float* qw2  = (const float*)d_in[6];
    const float* kvw1 = (const float*)d_in[7];
    const float* kvw2 = (const float*)d_in[8];
    const float* qnw  = (const float*)d_in[9];
    const float* qnb  = (const float*)d_in[10];
    const float* knw  = (const float*)d_in[11];
    const float* knb  = (const float*)d_in[12];
    const float* pxw1 = (const float*)d_in[13];
    const float* pxw2 = (const float*)d_in[14];
    const float* phw1 = (const float*)d_in[15];
    const float* phb1 = (const float*)d_in[16];
    const float* phw2 = (const float*)d_in[17];
    const float* phb2 = (const float*)d_in[18];

    float* out = (float*)d_out;
    char*  ws  = (char*)d_ws;

    size_t off = 0;
    float* Xn4 = (float*)(ws + off);          off += (size_t)NTOT*4*4;
    float* Qn  = (float*)(ws + off);          off += (size_t)NTOT*64*4;
    unsigned short* Ptb = (unsigned short*)(ws + off); off += (size_t)NTOT*PSTR*2;
    float* Ab  = (float*)(ws + off);          off += (size_t)NTOT*64*4;
    unsigned short* w2x   = (unsigned short*)(ws + off); off += (size_t)192*PSTR*2;
    unsigned short* qw1T  = (unsigned short*)(ws + off); off += (size_t)64*WS72*2;
    unsigned short* qw2T  = (unsigned short*)(ws + off); off += (size_t)64*WS72*2;
    unsigned short* kvw1T = (unsigned short*)(ws + off); off += (size_t)128*WS72*2;
    unsigned short* phh1T = (unsigned short*)(ws + off); off += (size_t)64*WS72*2;
    unsigned short* phh2T = (unsigned short*)(ws + off); off += (size_t)64*WS72*2;

    k0_prep<<<128, 256, 0, stream>>>(kvw2, pxw1, X, xw, qw1, qw2, kvw1,
                                     phw1, phw2, w2x, Xn4,
                                     qw1T, qw2T, kvw1T, phh1T, phh2T);
    k2_node<<<256, 128, 0, stream>>>(H, qw1T, qw2T, kvw1T, qnw, qnb, Qn, Ptb);
    k3_edge<<<512, 512, 0, stream>>>(Xn4, Qn, Ptb, w2x, kvw1, knw, knb,
                                     pxw2, Ab, out);
    k4_hout<<<256, 128, 0, stream>>>(H, Ab, phh1T, phb1, phh2T, phb2,
                                     out + NTOT*3);
}

// Round 7
// 184.872 us; speedup vs baseline: 1.1216x; 1.0641x over previous
//
#include <hip/hip_runtime.h>
#include <math.h>

// Problem constants (fixed by setup_inputs)
#define NB     128
#define NNODE  64
#define NTOT   8192
#define DIM    64
#define PSTR   136     // padded k-stride (bf16 elems) for Ptb / w2x rows
#define WS72   72      // padded k-stride for small 64-k weight transposes

typedef __bf16 bf16x8 __attribute__((ext_vector_type(8)));
typedef float  f32x4  __attribute__((ext_vector_type(4)));

__device__ __forceinline__ float frcp(float x) {
    return __builtin_amdgcn_rcpf(x);
}

__device__ __forceinline__ float silu_f(float x) {
    return x * frcp(1.0f + __expf(-x));
}

__device__ __forceinline__ unsigned short bf16bits(float f) {
    return __builtin_bit_cast(unsigned short, (__bf16)f);
}

__device__ __forceinline__ bf16x8 to_bf16x8(const float* v) {
    bf16x8 o;
    #pragma unroll
    for (int j = 0; j < 8; ++j) o[j] = (__bf16)v[j];
    return o;
}

__device__ __forceinline__ float wsum(float v) {
    #pragma unroll
    for (int m = 1; m < 64; m <<= 1) v += __shfl_xor(v, m, 64);
    return v;
}

// ---------------------------------------------------------------------------
// K0: prep transposed bf16 weights + xnorm. grid 128 x 256.
// ---------------------------------------------------------------------------
__global__ __launch_bounds__(256) void k0_prep(
        const float* __restrict__ kvw2, const float* __restrict__ phxw1,
        const float* __restrict__ X, const float* __restrict__ xw,
        const float* __restrict__ qw1, const float* __restrict__ qw2,
        const float* __restrict__ kvw1,
        const float* __restrict__ phh1, const float* __restrict__ phh2,
        unsigned short* __restrict__ w2x, float* __restrict__ Xn4,
        unsigned short* __restrict__ qw1T, unsigned short* __restrict__ qw2T,
        unsigned short* __restrict__ kvw1T,
        unsigned short* __restrict__ phh1T, unsigned short* __restrict__ phh2T) {
    const int k = blockIdx.x;       // 0..127 : k-index and batch id
    const int T = threadIdx.x;
    if (T < 128) {
        w2x[T*PSTR + k] = bf16bits(kvw2[k*128 + T]);
    } else if (T < 192) {
        const int n2 = T - 128;
        float acc = 0.f;
        #pragma unroll 8
        for (int j = 0; j < 64; ++j)
            acc += kvw2[k*128 + 64 + j] * phxw1[j*64 + n2];
        w2x[(128 + n2)*PSTR + k] = bf16bits(acc);
    } else {
        const int L = T - 192;      // wave 3: xnorm for batch k
        const int n = k*64 + L;
        const float x0 = X[n*3+0], x1 = X[n*3+1], x2 = X[n*3+2];
        const float nm = sqrtf(x0*x0 + x1*x1 + x2*x2);
        const float mean = wsum(nm) * (1.0f/64.0f);
        const float sc = xw[0] * frcp(mean + 1e-5f);
        float4 o; o.x = x0*sc; o.y = x1*sc; o.z = x2*sc; o.w = 0.f;
        *(float4*)&Xn4[n*4] = o;
    }
    if (k < 64) {
        if (T < 128) kvw1T[T*WS72 + k] = bf16bits(kvw1[(1+k)*128 + T]);
    } else {
        const int kk = k - 64;
        if (T < 64)       qw1T[T*WS72 + kk]        = bf16bits(qw1[kk*64 + T]);
        else if (T < 128) qw2T[(T-64)*WS72 + kk]   = bf16bits(qw2[kk*64 + (T-64)]);
        else if (T < 192) phh1T[(T-128)*WS72 + kk] = bf16bits(phh1[kk*64 + (T-128)]);
        else              phh2T[(T-192)*WS72 + kk] = bf16bits(phh2[kk*64 + (T-192)]);
    }
}

// ---------------------------------------------------------------------------
// K2 (MFMA): 32-node tiles, 2 waves x 16 rows, grid 256 x 128.
// Weight B-frags staged in LDS (qw1T|qw2T|kvw1T contiguous in ws = 36864 B).
// ---------------------------------------------------------------------------
__global__ __launch_bounds__(128) void k2_node(
        const float* __restrict__ H,
        const unsigned short* __restrict__ qw1T,   // base of contiguous 256 rows
        const float* __restrict__ qnw, const float* __restrict__ qnb,
        float* __restrict__ Qn, unsigned short* __restrict__ Ptb) {
    const int nb = blockIdx.x * 32;
    const int T = threadIdx.x, w = T >> 6, L = T & 63;
    const int q = L >> 4, m = L & 15;
    __shared__ __align__(16) unsigned short swt[256*WS72];   // 36864 B
    __shared__ __align__(16) unsigned short zb[32*WS72];     // 4608 B

    {
        const uint4* s = (const uint4*)qw1T;
        uint4* d = (uint4*)swt;
        #pragma unroll
        for (int it = 0; it < 18; ++it) d[T + 128*it] = s[T + 128*it];
    }

    bf16x8 hf[2];
    #pragma unroll
    for (int ks = 0; ks < 2; ++ks) {
        float v[8];
        *(float4*)&v[0] = *(const float4*)&H[(size_t)(nb + w*16 + m)*64 + ks*32 + q*8];
        *(float4*)&v[4] = *(const float4*)&H[(size_t)(nb + w*16 + m)*64 + ks*32 + q*8 + 4];
        hf[ks] = to_bf16x8(v);
    }
    __syncthreads();

    // GEMM1: Z = silu(H @ qw1)   (swt rows 0..63)
    f32x4 acc[4];
    #pragma unroll
    for (int ct = 0; ct < 4; ++ct) acc[ct] = (f32x4){0.f,0.f,0.f,0.f};
    #pragma unroll
    for (int ks = 0; ks < 2; ++ks)
        #pragma unroll
        for (int ct = 0; ct < 4; ++ct) {
            const bf16x8 b = *(const bf16x8*)&swt[(ct*16 + m)*WS72 + ks*32 + q*8];
            acc[ct] = __builtin_amdgcn_mfma_f32_16x16x32_bf16(hf[ks], b, acc[ct], 0, 0, 0);
        }
    #pragma unroll
    for (int ct = 0; ct < 4; ++ct)
        #pragma unroll
        for (int r = 0; r < 4; ++r)
            zb[(w*16 + q*4 + r)*WS72 + ct*16 + m] = bf16bits(silu_f(acc[ct][r]));
    __syncthreads();

    // GEMM2: Z2 = Zs @ qw2 (swt rows 64..127), then LN
    bf16x8 zf[2];
    #pragma unroll
    for (int ks = 0; ks < 2; ++ks)
        zf[ks] = *(const bf16x8*)&zb[(w*16 + m)*WS72 + ks*32 + q*8];
    #pragma unroll
    for (int ct = 0; ct < 4; ++ct) acc[ct] = (f32x4){0.f,0.f,0.f,0.f};
    #pragma unroll
    for (int ks = 0; ks < 2; ++ks)
        #pragma unroll
        for (int ct = 0; ct < 4; ++ct) {
            const bf16x8 b = *(const bf16x8*)&swt[(64 + ct*16 + m)*WS72 + ks*32 + q*8];
            acc[ct] = __builtin_amdgcn_mfma_f32_16x16x32_bf16(zf[ks], b, acc[ct], 0, 0, 0);
        }
    float qnwv[4], qnbv[4];
    #pragma unroll
    for (int ct = 0; ct < 4; ++ct) { qnwv[ct] = qnw[ct*16+m]; qnbv[ct] = qnb[ct*16+m]; }
    #pragma unroll
    for (int r = 0; r < 4; ++r) {
        float s1 = 0.f, s2 = 0.f;
        #pragma unroll
        for (int ct = 0; ct < 4; ++ct) {
            const float z = acc[ct][r];
            s1 += z; s2 = fmaf(z, z, s2);
        }
        #pragma unroll
        for (int sh = 1; sh < 16; sh <<= 1) {
            s1 += __shfl_xor(s1, sh, 64);
            s2 += __shfl_xor(s2, sh, 64);
        }
        const float mu = s1 * (1.0f/64.0f);
        const float rstd = rsqrtf(s2 * (1.0f/64.0f) - mu*mu + 1e-5f);
        const int row = nb + w*16 + q*4 + r;
        #pragma unroll
        for (int ct = 0; ct < 4; ++ct)
            Qn[(size_t)row*64 + ct*16 + m] = (acc[ct][r] - mu)*rstd*qnwv[ct] + qnbv[ct];
    }

    // GEMM3: P = H @ kvw1[1:]  (swt rows 128..255), two 64-col halves
    #pragma unroll
    for (int ph = 0; ph < 2; ++ph) {
        #pragma unroll
        for (int ct = 0; ct < 4; ++ct) acc[ct] = (f32x4){0.f,0.f,0.f,0.f};
        #pragma unroll
        for (int ks = 0; ks < 2; ++ks)
            #pragma unroll
            for (int ct = 0; ct < 4; ++ct) {
                const bf16x8 b = *(const bf16x8*)&swt[(128 + ph*64 + ct*16 + m)*WS72 + ks*32 + q*8];
                acc[ct] = __builtin_amdgcn_mfma_f32_16x16x32_bf16(hf[ks], b, acc[ct], 0, 0, 0);
            }
        #pragma unroll
        for (int ct = 0; ct < 4; ++ct)
            #pragma unroll
            for (int r = 0; r < 4; ++r)
                Ptb[(size_t)(nb + w*16 + q*4 + r)*PSTR + ph*64 + ct*16 + m]
                    = bf16bits(acc[ct][r]);
    }
}

// ---------------------------------------------------------------------------
// K3: fused edge pipeline, pair-wave. Block = (graph, 8 dsts), 256 thr /
// 4 waves / 2 pairs; pair p owns dsts {i*2+p}, i=0..3; wave half h owns src
// rows [32h,32h+32). K|V weights in LDS (34.8 KB); G-weight B-frags read
// from global (17 KB, L1-resident after first dst). LDS ~42 KB -> 3
// blocks/CU; __launch_bounds__(256,3) -> 170-reg budget, no spill
// (~80 VGPR + 32 AGPR needed).
// ---------------------------------------------------------------------------
__global__ __launch_bounds__(256, 3) void k3_edge(
        const float* __restrict__ Xn4, const float* __restrict__ Qn,
        const unsigned short* __restrict__ Ptb,
        const unsigned short* __restrict__ w2x,
        const float* __restrict__ kvw1,
        const float* __restrict__ knw, const float* __restrict__ knb,
        const float* __restrict__ pxw2,
        float* __restrict__ Abuf, float* __restrict__ Xout) {
    const int bid = blockIdx.x;
    const int g = bid >> 3, dgrp = bid & 7;
    const int T = threadIdx.x, w = T >> 6, L = T & 63;
    const int q = L >> 4, m = L & 15;
    const int pair = w >> 1, half = w & 1;

    __shared__ __align__(16) unsigned short sw2[128*PSTR];  // 34816 B (K|V)
    __shared__ __align__(16) float sXn[64][4];              // 1024 B
    __shared__ __align__(16) float sQn[8][64];              // 2048 B
    __shared__ __align__(16) float sxr[4][32][4];           // 2048 B
    __shared__ float w0s[128];                              // 512 B
    __shared__ float knws[64], knbs[64], pxs[64];           // 768 B
    __shared__ float sred[2][2][2];
    __shared__ float sA[2][64];
    __shared__ float sX[2][4];

    // ---- staging (once per block) ----
    {
        const uint4* s1 = (const uint4*)w2x;
        uint4* d1 = (uint4*)sw2;
        #pragma unroll
        for (int it = 0; it < 9; ++it) {
            const int idx = T + 256*it;
            if (idx < 128*PSTR/8) d1[idx] = s1[idx];
        }
        const float* qsrc = Qn + ((size_t)g*64 + dgrp*8)*64;
        for (int idx = T; idx < 512; idx += 256)
            sQn[idx >> 6][idx & 63] = qsrc[idx];
        if (T < 64) *(float4*)&sXn[T][0] = *(const float4*)&Xn4[(g*64 + T)*4];
        if (T < 128) w0s[T] = kvw1[T];
        if (T < 64)            knws[T]       = knw[T];
        else if (T < 128)      knbs[T - 64]  = knb[T - 64];
        else if (T < 192)      pxs[T - 128]  = pxw2[T - 128];
    }
    __syncthreads();

    const unsigned short* PtG = Ptb + (size_t)g*64*PSTR;
    const unsigned short* Gw  = w2x + 128*PSTR;     // G-weight rows (global)

    #pragma unroll 1
    for (int i = 0; i < 4; ++i) {
        const int dql = i*2 + pair;         // 0..7 local dst
        const int dl  = dgrp*8 + dql;       // 0..63 in-graph dst
        const int d   = g*64 + dl;

        // ---- geometry for this wave's 32 src rows ----
        if (L < 32) {
            const int row = half*32 + L;
            const float4 xs  = *(const float4*)&sXn[row][0];
            const float4 xdv = *(const float4*)&sXn[dl][0];
            const float r0 = xs.x - xdv.x, r1 = xs.y - xdv.y, r2 = xs.z - xdv.z;
            const float rd = r0*r0 + r1*r1 + r2*r2;
            const float inv = frcp(1.0f + sqrtf(rd + 1e-8f));
            float4 o; o.x = r0*inv; o.y = r1*inv; o.z = r2*inv; o.w = rd;
            *(float4*)&sxr[w][L][0] = o;
        }
        asm volatile("s_waitcnt lgkmcnt(0)" ::: "memory");

        // ---- build t A-fragments (rows half*32 + rt*16 + m) ----
        bf16x8 af[2][4];
        float rdv[2];
        #pragma unroll
        for (int rt = 0; rt < 2; ++rt) rdv[rt] = sxr[w][rt*16 + m][3];
        #pragma unroll
        for (int ks = 0; ks < 4; ++ks) {
            float w0v[8];
            *(float4*)&w0v[0] = *(const float4*)&w0s[ks*32 + q*8];
            *(float4*)&w0v[4] = *(const float4*)&w0s[ks*32 + q*8 + 4];
            #pragma unroll
            for (int rt = 0; rt < 2; ++rt) {
                const int row = half*32 + rt*16 + m;
                const bf16x8 pb = *(const bf16x8*)&PtG[(size_t)row*PSTR + ks*32 + q*8];
                bf16x8 o;
                #pragma unroll
                for (int j = 0; j < 8; ++j) {
                    const float pf = (float)pb[j];
                    o[j] = (__bf16)silu_f(fmaf(rdv[rt], w0v[j], pf));
                }
                af[rt][ks] = o;
            }
        }

        f32x4 acc[4][2];

        // ---- K-pass: cols 0..63 (LDS) ----
        #pragma unroll
        for (int ct = 0; ct < 4; ++ct)
            #pragma unroll
            for (int rt = 0; rt < 2; ++rt)
                acc[ct][rt] = (f32x4){0.f, 0.f, 0.f, 0.f};
        #pragma unroll
        for (int ks = 0; ks < 4; ++ks)
            #pragma unroll
            for (int ct = 0; ct < 4; ++ct) {
                const bf16x8 b = *(const bf16x8*)&sw2[(ct*16 + m)*PSTR + ks*32 + q*8];
                #pragma unroll
                for (int rt = 0; rt < 2; ++rt)
                    acc[ct][rt] = __builtin_amdgcn_mfma_f32_16x16x32_bf16(
                                      af[rt][ks], b, acc[ct][rt], 0, 0, 0);
            }

        // ---- LN(K)+score ----
        float qdw[4], Sqdw = 0.f, Sqdb = 0.f;
        #pragma unroll
        for (int ct = 0; ct < 4; ++ct) {
            const float qd = sQn[dql][ct*16 + m];
            qdw[ct] = qd * knws[ct*16 + m];
            Sqdw += qdw[ct];
            Sqdb += qd * knbs[ct*16 + m];
        }
        #pragma unroll
        for (int sh = 1; sh < 16; sh <<= 1) {
            Sqdw += __shfl_xor(Sqdw, sh, 64);
            Sqdb += __shfl_xor(Sqdb, sh, 64);
        }
        float sc[2][4];
        #pragma unroll
        for (int rt = 0; rt < 2; ++rt)
            #pragma unroll
            for (int r = 0; r < 4; ++r) {
                float s1 = 0.f, s2 = 0.f, skq = 0.f;
                #pragma unroll
                for (int ct = 0; ct < 4; ++ct) {
                    const float kv = acc[ct][rt][r];
                    s1 += kv; s2 = fmaf(kv, kv, s2); skq = fmaf(kv, qdw[ct], skq);
                }
                #pragma unroll
                for (int sh = 1; sh < 16; sh <<= 1) {
                    s1  += __shfl_xor(s1,  sh, 64);
                    s2  += __shfl_xor(s2,  sh, 64);
                    skq += __shfl_xor(skq, sh, 64);
                }
                const float mu = s1 * (1.0f/64.0f);
                const float rstd = rsqrtf(s2 * (1.0f/64.0f) - mu*mu + 1e-5f);
                const float scv = (rstd * (skq - mu*Sqdw) + Sqdb) * 0.125f;
                const int row_g = half*32 + rt*16 + q*4 + r;
                sc[rt][r] = (row_g == dl) ? -1e30f : scv;
            }

        // ---- softmax: wave-local partial + cross-half rescale ----
        float mx = -1e30f;
        #pragma unroll
        for (int rt = 0; rt < 2; ++rt)
            #pragma unroll
            for (int r = 0; r < 4; ++r) mx = fmaxf(mx, sc[rt][r]);
        mx = fmaxf(mx, __shfl_xor(mx, 16, 64));
        mx = fmaxf(mx, __shfl_xor(mx, 32, 64));
        float al[2][4], S = 0.f;
        #pragma unroll
        for (int rt = 0; rt < 2; ++rt)
            #pragma unroll
            for (int r = 0; r < 4; ++r) {
                al[rt][r] = __expf(sc[rt][r] - mx);
                S += al[rt][r];
            }
        S += __shfl_xor(S, 16, 64);
        S += __shfl_xor(S, 32, 64);
        if (L == 0) { sred[pair][half][0] = mx; sred[pair][half][1] = S; }
        __syncthreads();                                    // b1
        {
            const float mo = sred[pair][half^1][0];
            const float So = sred[pair][half^1][1];
            const float M  = fmaxf(mx, mo);
            const float es = __expf(mx - M);
            const float eo = __expf(mo - M);
            const float alf = es * frcp(S*es + So*eo);
            #pragma unroll
            for (int rt = 0; rt < 2; ++rt)
                #pragma unroll
                for (int r = 0; r < 4; ++r) al[rt][r] *= alf;
        }

        // ---- V-pass: cols 64..127 (LDS) ----
        #pragma unroll
        for (int ct = 0; ct < 4; ++ct)
            #pragma unroll
            for (int rt = 0; rt < 2; ++rt)
                acc[ct][rt] = (f32x4){0.f, 0.f, 0.f, 0.f};
        #pragma unroll
        for (int ks = 0; ks < 4; ++ks)
            #pragma unroll
            for (int ct = 0; ct < 4; ++ct) {
                const bf16x8 b = *(const bf16x8*)&sw2[(64 + ct*16 + m)*PSTR + ks*32 + q*8];
                #pragma unroll
                for (int rt = 0; rt < 2; ++rt)
                    acc[ct][rt] = __builtin_amdgcn_mfma_f32_16x16x32_bf16(
                                      af[rt][ks], b, acc[ct][rt], 0, 0, 0);
            }
        float p[4];
        #pragma unroll
        for (int ct = 0; ct < 4; ++ct) {
            float pv = 0.f;
            #pragma unroll
            for (int rt = 0; rt < 2; ++rt)
                #pragma unroll
                for (int r = 0; r < 4; ++r)
                    pv = fmaf(al[rt][r], acc[ct][rt][r], pv);
            pv += __shfl_xor(pv, 16, 64);
            pv += __shfl_xor(pv, 32, 64);
            p[ct] = pv;
        }
        if (half == 1 && q == 0)
            #pragma unroll
            for (int ct = 0; ct < 4; ++ct) sA[pair][ct*16 + m] = p[ct];
        __syncthreads();                                    // b2
        if (half == 0 && q == 0)
            #pragma unroll
            for (int ct = 0; ct < 4; ++ct)
                Abuf[(size_t)d*64 + ct*16 + m] = p[ct] + sA[pair][ct*16 + m];

        // ---- G-pass: B-frags from global (L1-resident) ----
        #pragma unroll
        for (int ct = 0; ct < 4; ++ct)
            #pragma unroll
            for (int rt = 0; rt < 2; ++rt)
                acc[ct][rt] = (f32x4){0.f, 0.f, 0.f, 0.f};
        #pragma unroll
        for (int ks = 0; ks < 4; ++ks)
            #pragma unroll
            for (int ct = 0; ct < 4; ++ct) {
                const bf16x8 b = *(const bf16x8*)&Gw[(size_t)(ct*16 + m)*PSTR + ks*32 + q*8];
                #pragma unroll
                for (int rt = 0; rt < 2; ++rt)
                    acc[ct][rt] = __builtin_amdgcn_mfma_f32_16x16x32_bf16(
                                      af[rt][ks], b, acc[ct][rt], 0, 0, 0);
            }

        // ---- phx epilogue + X partial ----
        float pxc[4];
        #pragma unroll
        for (int ct = 0; ct < 4; ++ct) pxc[ct] = pxs[ct*16 + m];
        float xa0 = 0.f, xa1 = 0.f, xa2 = 0.f;
        #pragma unroll
        for (int rt = 0; rt < 2; ++rt)
            #pragma unroll
            for (int r = 0; r < 4; ++r) {
                float ph = 0.f;
                #pragma unroll
                for (int ct = 0; ct < 4; ++ct)
                    ph = fmaf(silu_f(al[rt][r] * acc[ct][rt][r]), pxc[ct], ph);
                #pragma unroll
                for (int sh = 1; sh < 16; sh <<= 1) ph += __shfl_xor(ph, sh, 64);
                const float4 xr = *(const float4*)&sxr[w][rt*16 + q*4 + r][0];
                xa0 = fmaf(ph, xr.x, xa0);
                xa1 = fmaf(ph, xr.y, xa1);
                xa2 = fmaf(ph, xr.z, xa2);
            }
        xa0 += __shfl_xor(xa0, 16, 64); xa0 += __shfl_xor(xa0, 32, 64);
        xa1 += __shfl_xor(xa1, 16, 64); xa1 += __shfl_xor(xa1, 32, 64);
        xa2 += __shfl_xor(xa2, 16, 64); xa2 += __shfl_xor(xa2, 32, 64);
        if (half == 1 && L == 0) {
            sX[pair][0] = xa0; sX[pair][1] = xa1; sX[pair][2] = xa2;
        }
        __syncthreads();                                    // b3
        if (half == 0 && L == 0) {
            const float4 xdv = *(const float4*)&sXn[dl][0];
            Xout[(size_t)d*3 + 0] = xdv.x + xa0 + sX[pair][0];
            Xout[(size_t)d*3 + 1] = xdv.y + xa1 + sX[pair][1];
            Xout[(size_t)d*3 + 2] = xdv.z + xa2 + sX[pair][2];
        }
    }
}

// ---------------------------------------------------------------------------
// K4 (MFMA): H_out = H + silu((A*A*H)@phh1 + b1)@phh2 + b2, 32-node tiles.
// Weights staged in LDS (phh1T|phh2T contiguous = 18432 B).
// ---------------------------------------------------------------------------
__global__ __launch_bounds__(128) void k4_hout(
        const float* __restrict__ H, const float* __restrict__ Abuf,
        const unsigned short* __restrict__ phh1T, const float* __restrict__ b1,
        const float* __restrict__ b2, float* __restrict__ Hout) {
    const int nb = blockIdx.x * 32;
    const int T = threadIdx.x, w = T >> 6, L = T & 63;
    const int q = L >> 4, m = L & 15;
    __shared__ __align__(16) unsigned short swt[128*WS72];   // 18432 B
    __shared__ __align__(16) unsigned short zb[32*WS72];

    {
        const uint4* s = (const uint4*)phh1T;
        uint4* d = (uint4*)swt;
        #pragma unroll
        for (int it = 0; it < 9; ++it) d[T + 128*it] = s[T + 128*it];
    }

    bf16x8 uf[2];
    #pragma unroll
    for (int ks = 0; ks < 2; ++ks) {
        const size_t base = (size_t)(nb + w*16 + m)*64 + ks*32 + q*8;
        float a[8], h[8], v[8];
        *(float4*)&a[0] = *(const float4*)&Abuf[base];
        *(float4*)&a[4] = *(const float4*)&Abuf[base + 4];
        *(float4*)&h[0] = *(const float4*)&H[base];
        *(float4*)&h[4] = *(const float4*)&H[base + 4];
        #pragma unroll
        for (int j = 0; j < 8; ++j) v[j] = a[j]*a[j]*h[j];
        uf[ks] = to_bf16x8(v);
    }
    __syncthreads();

    f32x4 acc[4];
    #pragma unroll
    for (int ct = 0; ct < 4; ++ct) acc[ct] = (f32x4){0.f,0.f,0.f,0.f};
    #pragma unroll
    for (int ks = 0; ks < 2; ++ks)
        #pragma unroll
        for (int ct = 0; ct < 4; ++ct) {
            const bf16x8 b = *(const bf16x8*)&swt[(ct*16 + m)*WS72 + ks*32 + q*8];
            acc[ct] = __builtin_amdgcn_mfma_f32_16x16x32_bf16(uf[ks], b, acc[ct], 0, 0, 0);
        }
    #pragma unroll
    for (int ct = 0; ct < 4; ++ct) {
        const float bv = b1[ct*16 + m];
        #pragma unroll
        for (int r = 0; r < 4; ++r)
            zb[(w*16 + q*4 + r)*WS72 + ct*16 + m] = bf16bits(silu_f(acc[ct][r] + bv));
    }
    __syncthreads();

    bf16x8 zf[2];
    #pragma unroll
    for (int ks = 0; ks < 2; ++ks)
        zf[ks] = *(const bf16x8*)&zb[(w*16 + m)*WS72 + ks*32 + q*8];
    #pragma unroll
    for (int ct = 0; ct < 4; ++ct) acc[ct] = (f32x4){0.f,0.f,0.f,0.f};
    #pragma unroll
    for (int ks = 0; ks < 2; ++ks)
        #pragma unroll
        for (int ct = 0; ct < 4; ++ct) {
            const bf16x8 b = *(const bf16x8*)&swt[(64 + ct*16 + m)*WS72 + ks*32 + q*8];
            acc[ct] = __builtin_amdgcn_mfma_f32_16x16x32_bf16(zf[ks], b, acc[ct], 0, 0, 0);
        }
    #pragma unroll
    for (int ct = 0; ct < 4; ++ct) {
        const float bv = b2[ct*16 + m];
        #pragma unroll
        for (int r = 0; r < 4; ++r) {
            const size_t idx = (size_t)(nb + w*16 + q*4 + r)*64 + ct*16 + m;
            Hout[idx] = H[idx] + acc[ct][r] + bv;
        }
    }
}

// ---------------------------------------------------------------------------
extern "C" void kernel_launch(void* const* d_in, const int* in_sizes, int n_in,
                              void* d_out, int out_size, void* d_ws, size_t ws_size,
                              hipStream_t stream) {
    const float* X    = (const float*)d_in[1];
    const float* H    = (const float*)d_in[2];
    const float* xw   = (const float*)d_in[4];
    const float* qw1  = (const float*)d_in[5];
    const float* qw2  = (const float*)d_in[6];
    const float* kvw1 = (const float*)d_in[7];
    const float* kvw2 = (const float*)d_in[8];
    const float* qnw  = (const float*)d_in[9];
    const float* qnb  = (const float*)d_in[10];
    const float* knw  = (const float*)d_in[11];
    const float* knb  = (const float*)d_in[12];
    const float* pxw1 = (const float*)d_in[13];
    const float* pxw2 = (const float*)d_in[14];
    const float* phw1 = (const float*)d_in[15];
    const float* phb1 = (const float*)d_in[16];
    const float* phw2 = (const float*)d_in[17];
    const float* phb2 = (const float*)d_in[18];

    float* out = (float*)d_out;
    char*  ws  = (char*)d_ws;

    size_t off = 0;
    float* Xn4 = (float*)(ws + off);          off += (size_t)NTOT*4*4;
    float* Qn  = (float*)(ws + off);          off += (size_t)NTOT*64*4;
    unsigned short* Ptb = (unsigned short*)(ws + off); off += (size_t)NTOT*PSTR*2;
    float* Ab  = (float*)(ws + off);          off += (size_t)NTOT*64*4;
    unsigned short* w2x   = (unsigned short*)(ws + off); off += (size_t)192*PSTR*2;
    // k2 weights contiguous: qw1T | qw2T | kvw1T  (256 rows x WS72)
    unsigned short* qw1T  = (unsigned short*)(ws + off); off += (size_t)64*WS72*2;
    unsigned short* qw2T  = (unsigned short*)(ws + off); off += (size_t)64*WS72*2;
    unsigned short* kvw1T = (unsigned short*)(ws + off); off += (size_t)128*WS72*2;
    // k4 weights contiguous: phh1T | phh2T  (128 rows x WS72)
    unsigned short* phh1T = (unsigned short*)(ws + off); off += (size_t)64*WS72*2;
    unsigned short* phh2T = (unsigned short*)(ws + off); off += (size_t)64*WS72*2;

    k0_prep<<<128, 256, 0, stream>>>(kvw2, pxw1, X, xw, qw1, qw2, kvw1,
                                     phw1, phw2, w2x, Xn4,
                                     qw1T, qw2T, kvw1T, phh1T, phh2T);
    k2_node<<<256, 128, 0, stream>>>(H, qw1T, qnw, qnb, Qn, Ptb);
    k3_edge<<<1024, 256, 0, stream>>>(Xn4, Qn, Ptb, w2x, kvw1, knw, knb,
                                      pxw2, Ab, out);
    k4_hout<<<256, 128, 0, stream>>>(H, Ab, phh1T, phb1, phb2, out + NTOT*3);
}

// Round 8
// 173.135 us; speedup vs baseline: 1.1976x; 1.0678x over previous
//
#include <hip/hip_runtime.h>
#include <math.h>

// Problem constants (fixed by setup_inputs)
#define NB     128
#define NNODE  64
#define NTOT   8192
#define DIM    64
#define PSTR   136     // padded k-stride (bf16 elems) for Ptb / w2x rows
#define WS72   72      // padded k-stride for small 64-k weight transposes

typedef __bf16 bf16x8 __attribute__((ext_vector_type(8)));
typedef float  f32x4  __attribute__((ext_vector_type(4)));

__device__ __forceinline__ float frcp(float x) {
    return __builtin_amdgcn_rcpf(x);
}

__device__ __forceinline__ float silu_f(float x) {
    return x * frcp(1.0f + __expf(-x));
}

__device__ __forceinline__ unsigned short bf16bits(float f) {
    return __builtin_bit_cast(unsigned short, (__bf16)f);
}

__device__ __forceinline__ bf16x8 to_bf16x8(const float* v) {
    bf16x8 o;
    #pragma unroll
    for (int j = 0; j < 8; ++j) o[j] = (__bf16)v[j];
    return o;
}

__device__ __forceinline__ float wsum(float v) {
    #pragma unroll
    for (int m = 1; m < 64; m <<= 1) v += __shfl_xor(v, m, 64);
    return v;
}

// ---- DPP 16-lane reduction: total lands in lane m=15 of each 16-group ----
template<int CTRL>
__device__ __forceinline__ float dpp_add(float v) {
    const int r = __builtin_amdgcn_update_dpp(
        0, __builtin_bit_cast(int, v), CTRL, 0xF, 0xF, true);
    return v + __builtin_bit_cast(float, r);
}
__device__ __forceinline__ float row_sum16(float v) {
    v = dpp_add<0x111>(v);   // row_shr:1
    v = dpp_add<0x112>(v);   // row_shr:2
    v = dpp_add<0x114>(v);   // row_shr:4
    v = dpp_add<0x118>(v);   // row_shr:8
    return v;                // m==15 holds the 16-lane sum
}
// broadcast lane 15 of each 16-group to all 16 lanes
__device__ __forceinline__ float bcast15(float v) {
    return __builtin_bit_cast(float,
        __builtin_amdgcn_ds_swizzle(__builtin_bit_cast(int, v), 0x01F0));
}

// ---------------------------------------------------------------------------
// K0: prep transposed bf16 weights + xnorm. grid 128 x 256.
// ---------------------------------------------------------------------------
__global__ __launch_bounds__(256) void k0_prep(
        const float* __restrict__ kvw2, const float* __restrict__ phxw1,
        const float* __restrict__ X, const float* __restrict__ xw,
        const float* __restrict__ qw1, const float* __restrict__ qw2,
        const float* __restrict__ kvw1,
        const float* __restrict__ phh1, const float* __restrict__ phh2,
        unsigned short* __restrict__ w2x, float* __restrict__ Xn4,
        unsigned short* __restrict__ qw1T, unsigned short* __restrict__ qw2T,
        unsigned short* __restrict__ kvw1T,
        unsigned short* __restrict__ phh1T, unsigned short* __restrict__ phh2T) {
    const int k = blockIdx.x;       // 0..127 : k-index and batch id
    const int T = threadIdx.x;
    if (T < 128) {
        w2x[T*PSTR + k] = bf16bits(kvw2[k*128 + T]);
    } else if (T < 192) {
        const int n2 = T - 128;
        float acc = 0.f;
        #pragma unroll 8
        for (int j = 0; j < 64; ++j)
            acc += kvw2[k*128 + 64 + j] * phxw1[j*64 + n2];
        w2x[(128 + n2)*PSTR + k] = bf16bits(acc);
    } else {
        const int L = T - 192;      // wave 3: xnorm for batch k
        const int n = k*64 + L;
        const float x0 = X[n*3+0], x1 = X[n*3+1], x2 = X[n*3+2];
        const float nm = sqrtf(x0*x0 + x1*x1 + x2*x2);
        const float mean = wsum(nm) * (1.0f/64.0f);
        const float sc = xw[0] * frcp(mean + 1e-5f);
        float4 o; o.x = x0*sc; o.y = x1*sc; o.z = x2*sc; o.w = 0.f;
        *(float4*)&Xn4[n*4] = o;
    }
    if (k < 64) {
        if (T < 128) kvw1T[T*WS72 + k] = bf16bits(kvw1[(1+k)*128 + T]);
    } else {
        const int kk = k - 64;
        if (T < 64)       qw1T[T*WS72 + kk]        = bf16bits(qw1[kk*64 + T]);
        else if (T < 128) qw2T[(T-64)*WS72 + kk]   = bf16bits(qw2[kk*64 + (T-64)]);
        else if (T < 192) phh1T[(T-128)*WS72 + kk] = bf16bits(phh1[kk*64 + (T-128)]);
        else              phh2T[(T-192)*WS72 + kk] = bf16bits(phh2[kk*64 + (T-192)]);
    }
}

// ---------------------------------------------------------------------------
// K2 (MFMA): single-wave 16-node tiles, role-split blocks. grid 1024 x 64.
//  role 0: Qn = LN(silu(H@qw1)@qw2)    role 1: Ptb = bf16(H@kvw1[1:])
//  B-frags straight from global (L2-hot, no LDS staging / no barrier).
// ---------------------------------------------------------------------------
__global__ __launch_bounds__(64) void k2_node(
        const float* __restrict__ H,
        const unsigned short* __restrict__ wbase,   // qw1T|qw2T|kvw1T
        const float* __restrict__ qnw, const float* __restrict__ qnb,
        float* __restrict__ Qn, unsigned short* __restrict__ Ptb) {
    const int tile = blockIdx.x >> 1, role = blockIdx.x & 1;
    const int nb = tile * 16;
    const int L = threadIdx.x, q = L >> 4, m = L & 15;
    __shared__ __align__(16) unsigned short zb[16*WS72];

    bf16x8 hf[2];
    #pragma unroll
    for (int ks = 0; ks < 2; ++ks) {
        float v[8];
        *(float4*)&v[0] = *(const float4*)&H[(size_t)(nb + m)*64 + ks*32 + q*8];
        *(float4*)&v[4] = *(const float4*)&H[(size_t)(nb + m)*64 + ks*32 + q*8 + 4];
        hf[ks] = to_bf16x8(v);
    }

    f32x4 acc[4];
    if (role == 1) {
        const unsigned short* kvw1T = wbase + 128*WS72;
        #pragma unroll
        for (int ph = 0; ph < 2; ++ph) {
            #pragma unroll
            for (int ct = 0; ct < 4; ++ct) acc[ct] = (f32x4){0.f,0.f,0.f,0.f};
            #pragma unroll
            for (int ks = 0; ks < 2; ++ks)
                #pragma unroll
                for (int ct = 0; ct < 4; ++ct) {
                    const bf16x8 b = *(const bf16x8*)&kvw1T[(ph*64 + ct*16 + m)*WS72 + ks*32 + q*8];
                    acc[ct] = __builtin_amdgcn_mfma_f32_16x16x32_bf16(hf[ks], b, acc[ct], 0, 0, 0);
                }
            #pragma unroll
            for (int ct = 0; ct < 4; ++ct)
                #pragma unroll
                for (int r = 0; r < 4; ++r)
                    Ptb[(size_t)(nb + q*4 + r)*PSTR + ph*64 + ct*16 + m]
                        = bf16bits(acc[ct][r]);
        }
        return;
    }

    // role 0: GEMM1 Z = silu(H@qw1)
    #pragma unroll
    for (int ct = 0; ct < 4; ++ct) acc[ct] = (f32x4){0.f,0.f,0.f,0.f};
    #pragma unroll
    for (int ks = 0; ks < 2; ++ks)
        #pragma unroll
        for (int ct = 0; ct < 4; ++ct) {
            const bf16x8 b = *(const bf16x8*)&wbase[(ct*16 + m)*WS72 + ks*32 + q*8];
            acc[ct] = __builtin_amdgcn_mfma_f32_16x16x32_bf16(hf[ks], b, acc[ct], 0, 0, 0);
        }
    #pragma unroll
    for (int ct = 0; ct < 4; ++ct)
        #pragma unroll
        for (int r = 0; r < 4; ++r)
            zb[(q*4 + r)*WS72 + ct*16 + m] = bf16bits(silu_f(acc[ct][r]));

    // single wave: compiler inserts lgkmcnt waits for zb RAW
    bf16x8 zf[2];
    #pragma unroll
    for (int ks = 0; ks < 2; ++ks)
        zf[ks] = *(const bf16x8*)&zb[m*WS72 + ks*32 + q*8];
    const unsigned short* qw2T = wbase + 64*WS72;
    #pragma unroll
    for (int ct = 0; ct < 4; ++ct) acc[ct] = (f32x4){0.f,0.f,0.f,0.f};
    #pragma unroll
    for (int ks = 0; ks < 2; ++ks)
        #pragma unroll
        for (int ct = 0; ct < 4; ++ct) {
            const bf16x8 b = *(const bf16x8*)&qw2T[(ct*16 + m)*WS72 + ks*32 + q*8];
            acc[ct] = __builtin_amdgcn_mfma_f32_16x16x32_bf16(zf[ks], b, acc[ct], 0, 0, 0);
        }
    float qnwv[4], qnbv[4];
    #pragma unroll
    for (int ct = 0; ct < 4; ++ct) { qnwv[ct] = qnw[ct*16+m]; qnbv[ct] = qnb[ct*16+m]; }
    #pragma unroll
    for (int r = 0; r < 4; ++r) {
        float s1 = 0.f, s2 = 0.f;
        #pragma unroll
        for (int ct = 0; ct < 4; ++ct) {
            const float z = acc[ct][r];
            s1 += z; s2 = fmaf(z, z, s2);
        }
        #pragma unroll
        for (int sh = 1; sh < 16; sh <<= 1) {
            s1 += __shfl_xor(s1, sh, 64);
            s2 += __shfl_xor(s2, sh, 64);
        }
        const float mu = s1 * (1.0f/64.0f);
        const float rstd = rsqrtf(s2 * (1.0f/64.0f) - mu*mu + 1e-5f);
        const int row = nb + q*4 + r;
        #pragma unroll
        for (int ct = 0; ct < 4; ++ct)
            Qn[(size_t)row*64 + ct*16 + m] = (acc[ct][r] - mu)*rstd*qnwv[ct] + qnbv[ct];
    }
}

// ---------------------------------------------------------------------------
// K3: fused edge pipeline, pair-wave + DPP reductions. Block = (graph,
// 8 dsts), 256 thr / 2 pairs; wave half h owns src rows [32h,32h+32).
// 16-lane reductions on the VALU (DPP row_shr), score broadcast via one
// ds_swizzle. 2 barriers per dst-iter. K|V weights in LDS; G weights global.
// ---------------------------------------------------------------------------
__global__ __launch_bounds__(256, 3) void k3_edge(
        const float* __restrict__ Xn4, const float* __restrict__ Qn,
        const unsigned short* __restrict__ Ptb,
        const unsigned short* __restrict__ w2x,
        const float* __restrict__ kvw1,
        const float* __restrict__ knw, const float* __restrict__ knb,
        const float* __restrict__ pxw2,
        float* __restrict__ Abuf, float* __restrict__ Xout) {
    const int bid = blockIdx.x;
    const int g = bid >> 3, dgrp = bid & 7;
    const int T = threadIdx.x, w = T >> 6, L = T & 63;
    const int q = L >> 4, m = L & 15;
    const int pair = w >> 1, half = w & 1;

    __shared__ __align__(16) unsigned short sw2[128*PSTR];  // 34816 B (K|V)
    __shared__ __align__(16) float sXn[64][4];              // 1024 B
    __shared__ __align__(16) float sQn[8][64];              // 2048 B
    __shared__ __align__(16) float sxr[4][32][4];           // 2048 B
    __shared__ float w0s[128];                              // 512 B
    __shared__ float knws[64], knbs[64], pxs[64];           // 768 B
    __shared__ float sred[2][2][2];
    __shared__ float sA[2][64];
    __shared__ float sX[2][4];

    // ---- staging (once per block) ----
    {
        const uint4* s1 = (const uint4*)w2x;
        uint4* d1 = (uint4*)sw2;
        #pragma unroll
        for (int it = 0; it < 9; ++it) {
            const int idx = T + 256*it;
            if (idx < 128*PSTR/8) d1[idx] = s1[idx];
        }
        const float* qsrc = Qn + ((size_t)g*64 + dgrp*8)*64;
        for (int idx = T; idx < 512; idx += 256)
            sQn[idx >> 6][idx & 63] = qsrc[idx];
        if (T < 64) *(float4*)&sXn[T][0] = *(const float4*)&Xn4[(g*64 + T)*4];
        if (T < 128) w0s[T] = kvw1[T];
        if (T < 64)            knws[T]       = knw[T];
        else if (T < 128)      knbs[T - 64]  = knb[T - 64];
        else if (T < 192)      pxs[T - 128]  = pxw2[T - 128];
    }
    __syncthreads();

    const unsigned short* PtG = Ptb + (size_t)g*64*PSTR;
    const unsigned short* Gw  = w2x + 128*PSTR;     // G-weight rows (global)
    const float mflag = (m == 15) ? 1.0f : 0.0f;

    #pragma unroll 1
    for (int i = 0; i < 4; ++i) {
        const int dql = i*2 + pair;         // 0..7 local dst
        const int dl  = dgrp*8 + dql;       // 0..63 in-graph dst
        const int d   = g*64 + dl;

        // ---- geometry for this wave's 32 src rows ----
        if (L < 32) {
            const int row = half*32 + L;
            const float4 xs  = *(const float4*)&sXn[row][0];
            const float4 xdv = *(const float4*)&sXn[dl][0];
            const float r0 = xs.x - xdv.x, r1 = xs.y - xdv.y, r2 = xs.z - xdv.z;
            const float rd = r0*r0 + r1*r1 + r2*r2;
            const float inv = frcp(1.0f + sqrtf(rd + 1e-8f));
            float4 o; o.x = r0*inv; o.y = r1*inv; o.z = r2*inv; o.w = rd;
            *(float4*)&sxr[w][L][0] = o;
        }
        asm volatile("s_waitcnt lgkmcnt(0)" ::: "memory");

        // ---- build t A-fragments (rows half*32 + rt*16 + m) ----
        bf16x8 af[2][4];
        float rdv[2];
        #pragma unroll
        for (int rt = 0; rt < 2; ++rt) rdv[rt] = sxr[w][rt*16 + m][3];
        #pragma unroll
        for (int ks = 0; ks < 4; ++ks) {
            float w0v[8];
            *(float4*)&w0v[0] = *(const float4*)&w0s[ks*32 + q*8];
            *(float4*)&w0v[4] = *(const float4*)&w0s[ks*32 + q*8 + 4];
            #pragma unroll
            for (int rt = 0; rt < 2; ++rt) {
                const int row = half*32 + rt*16 + m;
                const bf16x8 pb = *(const bf16x8*)&PtG[(size_t)row*PSTR + ks*32 + q*8];
                bf16x8 o;
                #pragma unroll
                for (int j = 0; j < 8; ++j) {
                    const float pf = (float)pb[j];
                    o[j] = (__bf16)silu_f(fmaf(rdv[rt], w0v[j], pf));
                }
                af[rt][ks] = o;
            }
        }

        f32x4 acc[4][2];

        // ---- K-pass: cols 0..63 (LDS) ----
        #pragma unroll
        for (int ct = 0; ct < 4; ++ct)
            #pragma unroll
            for (int rt = 0; rt < 2; ++rt)
                acc[ct][rt] = (f32x4){0.f, 0.f, 0.f, 0.f};
        #pragma unroll
        for (int ks = 0; ks < 4; ++ks)
            #pragma unroll
            for (int ct = 0; ct < 4; ++ct) {
                const bf16x8 b = *(const bf16x8*)&sw2[(ct*16 + m)*PSTR + ks*32 + q*8];
                #pragma unroll
                for (int rt = 0; rt < 2; ++rt)
                    acc[ct][rt] = __builtin_amdgcn_mfma_f32_16x16x32_bf16(
                                      af[rt][ks], b, acc[ct][rt], 0, 0, 0);
            }

        // ---- LN(K)+score, DPP reductions (valid at m==15) ----
        float qdw[4], Sqdw = 0.f, Sqdb = 0.f;
        #pragma unroll
        for (int ct = 0; ct < 4; ++ct) {
            const float qd = sQn[dql][ct*16 + m];
            qdw[ct] = qd * knws[ct*16 + m];
            Sqdw += qdw[ct];
            Sqdb += qd * knbs[ct*16 + m];
        }
        Sqdw = row_sum16(Sqdw);
        Sqdb = row_sum16(Sqdb);
        float sc[2][4];
        #pragma unroll
        for (int rt = 0; rt < 2; ++rt)
            #pragma unroll
            for (int r = 0; r < 4; ++r) {
                float s1 = 0.f, s2 = 0.f, skq = 0.f;
                #pragma unroll
                for (int ct = 0; ct < 4; ++ct) {
                    const float kv = acc[ct][rt][r];
                    s1 += kv; s2 = fmaf(kv, kv, s2); skq = fmaf(kv, qdw[ct], skq);
                }
                s1  = row_sum16(s1);
                s2  = row_sum16(s2);
                skq = row_sum16(skq);
                const float mu = s1 * (1.0f/64.0f);
                const float rstd = rsqrtf(s2 * (1.0f/64.0f) - mu*mu + 1e-5f);
                float scv = (rstd * (skq - mu*Sqdw) + Sqdb) * 0.125f;
                scv = bcast15(scv);                 // one LDS op per row
                const int row_g = half*32 + rt*16 + q*4 + r;
                sc[rt][r] = (row_g == dl) ? -1e30f : scv;
            }

        // ---- softmax: wave-local partial + cross-half rescale ----
        float mx = -1e30f;
        #pragma unroll
        for (int rt = 0; rt < 2; ++rt)
            #pragma unroll
            for (int r = 0; r < 4; ++r) mx = fmaxf(mx, sc[rt][r]);
        mx = fmaxf(mx, __shfl_xor(mx, 16, 64));
        mx = fmaxf(mx, __shfl_xor(mx, 32, 64));
        float al[2][4], S = 0.f;
        #pragma unroll
        for (int rt = 0; rt < 2; ++rt)
            #pragma unroll
            for (int r = 0; r < 4; ++r) {
                al[rt][r] = __expf(sc[rt][r] - mx);
                S += al[rt][r];
            }
        S += __shfl_xor(S, 16, 64);
        S += __shfl_xor(S, 32, 64);
        if (L == 0) { sred[pair][half][0] = mx; sred[pair][half][1] = S; }
        __syncthreads();                                    // b1
        {
            const float mo = sred[pair][half^1][0];
            const float So = sred[pair][half^1][1];
            const float M  = fmaxf(mx, mo);
            const float es = __expf(mx - M);
            const float eo = __expf(mo - M);
            const float alf = es * frcp(S*es + So*eo);
            #pragma unroll
            for (int rt = 0; rt < 2; ++rt)
                #pragma unroll
                for (int r = 0; r < 4; ++r) al[rt][r] *= alf;
        }

        // ---- V-pass: cols 64..127 (LDS) ----
        #pragma unroll
        for (int ct = 0; ct < 4; ++ct)
            #pragma unroll
            for (int rt = 0; rt < 2; ++rt)
                acc[ct][rt] = (f32x4){0.f, 0.f, 0.f, 0.f};
        #pragma unroll
        for (int ks = 0; ks < 4; ++ks)
            #pragma unroll
            for (int ct = 0; ct < 4; ++ct) {
                const bf16x8 b = *(const bf16x8*)&sw2[(64 + ct*16 + m)*PSTR + ks*32 + q*8];
                #pragma unroll
                for (int rt = 0; rt < 2; ++rt)
                    acc[ct][rt] = __builtin_amdgcn_mfma_f32_16x16x32_bf16(
                                      af[rt][ks], b, acc[ct][rt], 0, 0, 0);
            }
        float p[4];
        #pragma unroll
        for (int ct = 0; ct < 4; ++ct) {
            float pv = 0.f;
            #pragma unroll
            for (int rt = 0; rt < 2; ++rt)
                #pragma unroll
                for (int r = 0; r < 4; ++r)
                    pv = fmaf(al[rt][r], acc[ct][rt][r], pv);
            pv += __shfl_xor(pv, 16, 64);
            pv += __shfl_xor(pv, 32, 64);
            p[ct] = pv;
        }

        // ---- G-pass: B-frags from global (L2-hot) ----
        #pragma unroll
        for (int ct = 0; ct < 4; ++ct)
            #pragma unroll
            for (int rt = 0; rt < 2; ++rt)
                acc[ct][rt] = (f32x4){0.f, 0.f, 0.f, 0.f};
        #pragma unroll
        for (int ks = 0; ks < 4; ++ks)
            #pragma unroll
            for (int ct = 0; ct < 4; ++ct) {
                const bf16x8 b = *(const bf16x8*)&Gw[(size_t)(ct*16 + m)*PSTR + ks*32 + q*8];
                #pragma unroll
                for (int rt = 0; rt < 2; ++rt)
                    acc[ct][rt] = __builtin_amdgcn_mfma_f32_16x16x32_bf16(
                                      af[rt][ks], b, acc[ct][rt], 0, 0, 0);
            }

        // ---- phx epilogue (DPP; ph valid at m==15) + X partial ----
        float pxc[4];
        #pragma unroll
        for (int ct = 0; ct < 4; ++ct) pxc[ct] = pxs[ct*16 + m];
        float xa0 = 0.f, xa1 = 0.f, xa2 = 0.f;
        #pragma unroll
        for (int rt = 0; rt < 2; ++rt)
            #pragma unroll
            for (int r = 0; r < 4; ++r) {
                float ph = 0.f;
                #pragma unroll
                for (int ct = 0; ct < 4; ++ct)
                    ph = fmaf(silu_f(al[rt][r] * acc[ct][rt][r]), pxc[ct], ph);
                ph = row_sum16(ph) * mflag;        // only m==15 contributes
                const float4 xr = *(const float4*)&sxr[w][rt*16 + q*4 + r][0];
                xa0 = fmaf(ph, xr.x, xa0);
                xa1 = fmaf(ph, xr.y, xa1);
                xa2 = fmaf(ph, xr.z, xa2);
            }
        xa0 += __shfl_xor(xa0, 16, 64); xa0 += __shfl_xor(xa0, 32, 64);
        xa1 += __shfl_xor(xa1, 16, 64); xa1 += __shfl_xor(xa1, 32, 64);
        xa2 += __shfl_xor(xa2, 16, 64); xa2 += __shfl_xor(xa2, 32, 64);
        // full sums now live in lanes with m==15

        if (half == 1) {
            if (q == 0)
                #pragma unroll
                for (int ct = 0; ct < 4; ++ct) sA[pair][ct*16 + m] = p[ct];
            if (L == 15) {
                sX[pair][0] = xa0; sX[pair][1] = xa1; sX[pair][2] = xa2;
            }
        }
        __syncthreads();                                    // b2 (merged)
        if (half == 0) {
            if (q == 0)
                #pragma unroll
                for (int ct = 0; ct < 4; ++ct)
                    Abuf[(size_t)d*64 + ct*16 + m] = p[ct] + sA[pair][ct*16 + m];
            if (L == 15) {
                const float4 xdv = *(const float4*)&sXn[dl][0];
                Xout[(size_t)d*3 + 0] = xdv.x + xa0 + sX[pair][0];
                Xout[(size_t)d*3 + 1] = xdv.y + xa1 + sX[pair][1];
                Xout[(size_t)d*3 + 2] = xdv.z + xa2 + sX[pair][2];
            }
        }
    }
}

// ---------------------------------------------------------------------------
// K4 (MFMA): single-wave 16-node tiles, grid 512 x 64, global B-frags.
// H_out = H + silu((A*A*H)@phh1 + b1)@phh2 + b2
// ---------------------------------------------------------------------------
__global__ __launch_bounds__(64) void k4_hout(
        const float* __restrict__ H, const float* __restrict__ Abuf,
        const unsigned short* __restrict__ wbase,   // phh1T|phh2T
        const float* __restrict__ b1, const float* __restrict__ b2,
        float* __restrict__ Hout) {
    const int nb = blockIdx.x * 16;
    const int L = threadIdx.x, q = L >> 4, m = L & 15;
    __shared__ __align__(16) unsigned short zb[16*WS72];

    bf16x8 uf[2];
    #pragma unroll
    for (int ks = 0; ks < 2; ++ks) {
        const size_t base = (size_t)(nb + m)*64 + ks*32 + q*8;
        float a[8], h[8], v[8];
        *(float4*)&a[0] = *(const float4*)&Abuf[base];
        *(float4*)&a[4] = *(const float4*)&Abuf[base + 4];
        *(float4*)&h[0] = *(const float4*)&H[base];
        *(float4*)&h[4] = *(const float4*)&H[base + 4];
        #pragma unroll
        for (int j = 0; j < 8; ++j) v[j] = a[j]*a[j]*h[j];
        uf[ks] = to_bf16x8(v);
    }

    f32x4 acc[4];
    #pragma unroll
    for (int ct = 0; ct < 4; ++ct) acc[ct] = (f32x4){0.f,0.f,0.f,0.f};
    #pragma unroll
    for (int ks = 0; ks < 2; ++ks)
        #pragma unroll
        for (int ct = 0; ct < 4; ++ct) {
            const bf16x8 b = *(const bf16x8*)&wbase[(ct*16 + m)*WS72 + ks*32 + q*8];
            acc[ct] = __builtin_amdgcn_mfma_f32_16x16x32_bf16(uf[ks], b, acc[ct], 0, 0, 0);
        }
    #pragma unroll
    for (int ct = 0; ct < 4; ++ct) {
        const float bv = b1[ct*16 + m];
        #pragma unroll
        for (int r = 0; r < 4; ++r)
            zb[(q*4 + r)*WS72 + ct*16 + m] = bf16bits(silu_f(acc[ct][r] + bv));
    }

    bf16x8 zf[2];
    #pragma unroll
    for (int ks = 0; ks < 2; ++ks)
        zf[ks] = *(const bf16x8*)&zb[m*WS72 + ks*32 + q*8];
    const unsigned short* phh2T = wbase + 64*WS72;
    #pragma unroll
    for (int ct = 0; ct < 4; ++ct) acc[ct] = (f32x4){0.f,0.f,0.f,0.f};
    #pragma unroll
    for (int ks = 0; ks < 2; ++ks)
        #pragma unroll
        for (int ct = 0; ct < 4; ++ct) {
            const bf16x8 b = *(const bf16x8*)&phh2T[(ct*16 + m)*WS72 + ks*32 + q*8];
            acc[ct] = __builtin_amdgcn_mfma_f32_16x16x32_bf16(zf[ks], b, acc[ct], 0, 0, 0);
        }
    #pragma unroll
    for (int ct = 0; ct < 4; ++ct) {
        const float bv = b2[ct*16 + m];
        #pragma unroll
        for (int r = 0; r < 4; ++r) {
            const size_t idx = (size_t)(nb + q*4 + r)*64 + ct*16 + m;
            Hout[idx] = H[idx] + acc[ct][r] + bv;
        }
    }
}

// ---------------------------------------------------------------------------
extern "C" void kernel_launch(void* const* d_in, const int* in_sizes, int n_in,
                              void* d_out, int out_size, void* d_ws, size_t ws_size,
                              hipStream_t stream) {
    const float* X    = (const float*)d_in[1];
    const float* H    = (const float*)d_in[2];
    const float* xw   = (const float*)d_in[4];
    const float* qw1  = (const float*)d_in[5];
    const float* qw2  = (const float*)d_in[6];
    const float* kvw1 = (const float*)d_in[7];
    const float* kvw2 = (const float*)d_in[8];
    const float* qnw  = (const float*)d_in[9];
    const float* qnb  = (const float*)d_in[10];
    const float* knw  = (const float*)d_in[11];
    const float* knb  = (const float*)d_in[12];
    const float* pxw1 = (const float*)d_in[13];
    const float* pxw2 = (const float*)d_in[14];
    const float* phw1 = (const float*)d_in[15];
    const float* phb1 = (const float*)d_in[16];
    const float* phw2 = (const float*)d_in[17];
    const float* phb2 = (const float*)d_in[18];

    float* out = (float*)d_out;
    char*  ws  = (char*)d_ws;

    size_t off = 0;
    float* Xn4 = (float*)(ws + off);          off += (size_t)NTOT*4*4;
    float* Qn  = (float*)(ws + off);          off += (size_t)NTOT*64*4;
    unsigned short* Ptb = (unsigned short*)(ws + off); off += (size_t)NTOT*PSTR*2;
    float* Ab  = (float*)(ws + off);          off += (size_t)NTOT*64*4;
    unsigned short* w2x   = (unsigned short*)(ws + off); off += (size_t)192*PSTR*2;
    // k2 weights contiguous: qw1T | qw2T | kvw1T  (256 rows x WS72)
    unsigned short* qw1T  = (unsigned short*)(ws + off); off += (size_t)64*WS72*2;
    unsigned short* qw2T  = (unsigned short*)(ws + off); off += (size_t)64*WS72*2;
    unsigned short* kvw1T = (unsigned short*)(ws + off); off += (size_t)128*WS72*2;
    // k4 weights contiguous: phh1T | phh2T  (128 rows x WS72)
    unsigned short* phh1T = (unsigned short*)(ws + off); off += (size_t)64*WS72*2;
    unsigned short* phh2T = (unsigned short*)(ws + off); off += (size_t)64*WS72*2;

    k0_prep<<<128, 256, 0, stream>>>(kvw2, pxw1, X, xw, qw1, qw2, kvw1,
                                     phw1, phw2, w2x, Xn4,
                                     qw1T, qw2T, kvw1T, phh1T, phh2T);
    k2_node<<<1024, 64, 0, stream>>>(H, qw1T, qnw, qnb, Qn, Ptb);
    k3_edge<<<1024, 256, 0, stream>>>(Xn4, Qn, Ptb, w2x, kvw1, knw, knb,
                                      pxw2, Ab, out);
    k4_hout<<<512, 64, 0, stream>>>(H, Ab, phh1T, phb1, phb2, out + NTOT*3);
}

// Round 9
// 165.529 us; speedup vs baseline: 1.2526x; 1.0459x over previous
//
#include <hip/hip_runtime.h>
#include <math.h>

// Problem constants (fixed by setup_inputs)
#define NB     128
#define NNODE  64
#define NTOT   8192
#define DIM    64
#define PSTR   136     // padded k-stride (bf16 elems) for Ptb / w2x rows
#define WS72   72      // padded k-stride for small 64-k weight transposes

typedef __bf16 bf16x8 __attribute__((ext_vector_type(8)));
typedef float  f32x4  __attribute__((ext_vector_type(4)));

__device__ __forceinline__ float frcp(float x) {
    return __builtin_amdgcn_rcpf(x);
}

__device__ __forceinline__ float silu_f(float x) {
    return x * frcp(1.0f + __expf(-x));
}

__device__ __forceinline__ unsigned short bf16bits(float f) {
    return __builtin_bit_cast(unsigned short, (__bf16)f);
}

__device__ __forceinline__ bf16x8 to_bf16x8(const float* v) {
    bf16x8 o;
    #pragma unroll
    for (int j = 0; j < 8; ++j) o[j] = (__bf16)v[j];
    return o;
}

__device__ __forceinline__ float wsum(float v) {
    #pragma unroll
    for (int m = 1; m < 64; m <<= 1) v += __shfl_xor(v, m, 64);
    return v;
}

// ---- DPP 16-lane reduction: total lands in lane m=15 of each 16-group ----
template<int CTRL>
__device__ __forceinline__ float dpp_add(float v) {
    const int r = __builtin_amdgcn_update_dpp(
        0, __builtin_bit_cast(int, v), CTRL, 0xF, 0xF, true);
    return v + __builtin_bit_cast(float, r);
}
__device__ __forceinline__ float row_sum16(float v) {
    v = dpp_add<0x111>(v);   // row_shr:1
    v = dpp_add<0x112>(v);   // row_shr:2
    v = dpp_add<0x114>(v);   // row_shr:4
    v = dpp_add<0x118>(v);   // row_shr:8
    return v;                // m==15 holds the 16-lane sum
}
// broadcast lane 15 of each 16-group to all 16 lanes
__device__ __forceinline__ float bcast15(float v) {
    return __builtin_bit_cast(float,
        __builtin_amdgcn_ds_swizzle(__builtin_bit_cast(int, v), 0x01F0));
}

// ---------------------------------------------------------------------------
// K0: prep transposed bf16 weights + xnorm. grid 128 x 256.
// ---------------------------------------------------------------------------
__global__ __launch_bounds__(256) void k0_prep(
        const float* __restrict__ kvw2, const float* __restrict__ phxw1,
        const float* __restrict__ X, const float* __restrict__ xw,
        const float* __restrict__ qw1, const float* __restrict__ qw2,
        const float* __restrict__ kvw1,
        const float* __restrict__ phh1, const float* __restrict__ phh2,
        unsigned short* __restrict__ w2x, float* __restrict__ Xn4,
        unsigned short* __restrict__ qw1T, unsigned short* __restrict__ qw2T,
        unsigned short* __restrict__ kvw1T,
        unsigned short* __restrict__ phh1T, unsigned short* __restrict__ phh2T) {
    const int k = blockIdx.x;       // 0..127 : k-index and batch id
    const int T = threadIdx.x;
    if (T < 128) {
        w2x[T*PSTR + k] = bf16bits(kvw2[k*128 + T]);
    } else if (T < 192) {
        const int n2 = T - 128;
        float acc = 0.f;
        #pragma unroll 8
        for (int j = 0; j < 64; ++j)
            acc += kvw2[k*128 + 64 + j] * phxw1[j*64 + n2];
        w2x[(128 + n2)*PSTR + k] = bf16bits(acc);
    } else {
        const int L = T - 192;      // wave 3: xnorm for batch k
        const int n = k*64 + L;
        const float x0 = X[n*3+0], x1 = X[n*3+1], x2 = X[n*3+2];
        const float nm = sqrtf(x0*x0 + x1*x1 + x2*x2);
        const float mean = wsum(nm) * (1.0f/64.0f);
        const float sc = xw[0] * frcp(mean + 1e-5f);
        float4 o; o.x = x0*sc; o.y = x1*sc; o.z = x2*sc; o.w = 0.f;
        *(float4*)&Xn4[n*4] = o;
    }
    if (k < 64) {
        if (T < 128) kvw1T[T*WS72 + k] = bf16bits(kvw1[(1+k)*128 + T]);
    } else {
        const int kk = k - 64;
        if (T < 64)       qw1T[T*WS72 + kk]        = bf16bits(qw1[kk*64 + T]);
        else if (T < 128) qw2T[(T-64)*WS72 + kk]   = bf16bits(qw2[kk*64 + (T-64)]);
        else if (T < 192) phh1T[(T-128)*WS72 + kk] = bf16bits(phh1[kk*64 + (T-128)]);
        else              phh2T[(T-192)*WS72 + kk] = bf16bits(phh2[kk*64 + (T-192)]);
    }
}

// ---------------------------------------------------------------------------
// K2 (MFMA): single-wave 16-node tiles, role-split blocks. grid 1024 x 64.
//  role 0: Qn = LN(silu(H@qw1)@qw2)    role 1: Ptb = bf16(H@kvw1[1:])
// ---------------------------------------------------------------------------
__global__ __launch_bounds__(64) void k2_node(
        const float* __restrict__ H,
        const unsigned short* __restrict__ wbase,   // qw1T|qw2T|kvw1T
        const float* __restrict__ qnw, const float* __restrict__ qnb,
        float* __restrict__ Qn, unsigned short* __restrict__ Ptb) {
    const int tile = blockIdx.x >> 1, role = blockIdx.x & 1;
    const int nb = tile * 16;
    const int L = threadIdx.x, q = L >> 4, m = L & 15;
    __shared__ __align__(16) unsigned short zb[16*WS72];

    bf16x8 hf[2];
    #pragma unroll
    for (int ks = 0; ks < 2; ++ks) {
        float v[8];
        *(float4*)&v[0] = *(const float4*)&H[(size_t)(nb + m)*64 + ks*32 + q*8];
        *(float4*)&v[4] = *(const float4*)&H[(size_t)(nb + m)*64 + ks*32 + q*8 + 4];
        hf[ks] = to_bf16x8(v);
    }

    f32x4 acc[4];
    if (role == 1) {
        const unsigned short* kvw1T = wbase + 128*WS72;
        #pragma unroll
        for (int ph = 0; ph < 2; ++ph) {
            #pragma unroll
            for (int ct = 0; ct < 4; ++ct) acc[ct] = (f32x4){0.f,0.f,0.f,0.f};
            #pragma unroll
            for (int ks = 0; ks < 2; ++ks)
                #pragma unroll
                for (int ct = 0; ct < 4; ++ct) {
                    const bf16x8 b = *(const bf16x8*)&kvw1T[(ph*64 + ct*16 + m)*WS72 + ks*32 + q*8];
                    acc[ct] = __builtin_amdgcn_mfma_f32_16x16x32_bf16(hf[ks], b, acc[ct], 0, 0, 0);
                }
            #pragma unroll
            for (int ct = 0; ct < 4; ++ct)
                #pragma unroll
                for (int r = 0; r < 4; ++r)
                    Ptb[(size_t)(nb + q*4 + r)*PSTR + ph*64 + ct*16 + m]
                        = bf16bits(acc[ct][r]);
        }
        return;
    }

    // role 0: GEMM1 Z = silu(H@qw1)
    #pragma unroll
    for (int ct = 0; ct < 4; ++ct) acc[ct] = (f32x4){0.f,0.f,0.f,0.f};
    #pragma unroll
    for (int ks = 0; ks < 2; ++ks)
        #pragma unroll
        for (int ct = 0; ct < 4; ++ct) {
            const bf16x8 b = *(const bf16x8*)&wbase[(ct*16 + m)*WS72 + ks*32 + q*8];
            acc[ct] = __builtin_amdgcn_mfma_f32_16x16x32_bf16(hf[ks], b, acc[ct], 0, 0, 0);
        }
    #pragma unroll
    for (int ct = 0; ct < 4; ++ct)
        #pragma unroll
        for (int r = 0; r < 4; ++r)
            zb[(q*4 + r)*WS72 + ct*16 + m] = bf16bits(silu_f(acc[ct][r]));

    bf16x8 zf[2];
    #pragma unroll
    for (int ks = 0; ks < 2; ++ks)
        zf[ks] = *(const bf16x8*)&zb[m*WS72 + ks*32 + q*8];
    const unsigned short* qw2T = wbase + 64*WS72;
    #pragma unroll
    for (int ct = 0; ct < 4; ++ct) acc[ct] = (f32x4){0.f,0.f,0.f,0.f};
    #pragma unroll
    for (int ks = 0; ks < 2; ++ks)
        #pragma unroll
        for (int ct = 0; ct < 4; ++ct) {
            const bf16x8 b = *(const bf16x8*)&qw2T[(ct*16 + m)*WS72 + ks*32 + q*8];
            acc[ct] = __builtin_amdgcn_mfma_f32_16x16x32_bf16(zf[ks], b, acc[ct], 0, 0, 0);
        }
    float qnwv[4], qnbv[4];
    #pragma unroll
    for (int ct = 0; ct < 4; ++ct) { qnwv[ct] = qnw[ct*16+m]; qnbv[ct] = qnb[ct*16+m]; }
    #pragma unroll
    for (int r = 0; r < 4; ++r) {
        float s1 = 0.f, s2 = 0.f;
        #pragma unroll
        for (int ct = 0; ct < 4; ++ct) {
            const float z = acc[ct][r];
            s1 += z; s2 = fmaf(z, z, s2);
        }
        #pragma unroll
        for (int sh = 1; sh < 16; sh <<= 1) {
            s1 += __shfl_xor(s1, sh, 64);
            s2 += __shfl_xor(s2, sh, 64);
        }
        const float mu = s1 * (1.0f/64.0f);
        const float rstd = rsqrtf(s2 * (1.0f/64.0f) - mu*mu + 1e-5f);
        const int row = nb + q*4 + r;
        #pragma unroll
        for (int ct = 0; ct < 4; ++ct)
            Qn[(size_t)row*64 + ct*16 + m] = (acc[ct][r] - mu)*rstd*qnwv[ct] + qnbv[ct];
    }
}

// ---------------------------------------------------------------------------
// K3: fused edge pipeline + H-MLP epilogue (k4 fused). Block = (graph,
// 8 dsts), 256 thr / 2 pairs; wave half h owns src rows [32h,32h+32).
// Incremental-ct accumulation keeps regs < 128 -> true 4 blocks/CU, and
// 1024 blocks = exactly 4/CU (no residency tail). A kept in LDS (bf16);
// wave 0 runs the 2-GEMM H-MLP at the end and writes H_out.
// ---------------------------------------------------------------------------
__global__ __launch_bounds__(256, 4) void k3_edge(
        const float* __restrict__ Xn4, const float* __restrict__ Qn,
        const unsigned short* __restrict__ Ptb,
        const unsigned short* __restrict__ w2x,
        const float* __restrict__ kvw1,
        const float* __restrict__ knw, const float* __restrict__ knb,
        const float* __restrict__ pxw2,
        const unsigned short* __restrict__ phhT,   // phh1T|phh2T
        const float* __restrict__ phb1, const float* __restrict__ phb2,
        const float* __restrict__ H,
        float* __restrict__ Hout, float* __restrict__ Xout) {
    const int bid = blockIdx.x;
    const int g = bid >> 3, dgrp = bid & 7;
    const int T = threadIdx.x, w = T >> 6, L = T & 63;
    const int q = L >> 4, m = L & 15;
    const int pair = w >> 1, half = w & 1;

    __shared__ __align__(16) unsigned short sw2[128*PSTR];  // 34816 B (K|V)
    __shared__ __align__(16) float sxr[4][32][4];           // 2048 B
    __shared__ __align__(16) unsigned short sAb[8*WS72];    // 1152 B
    __shared__ float w0s[128];                              // 512 B
    __shared__ float knws[64], knbs[64], pxs[64];           // 768 B
    __shared__ float sred[2][2][2];
    __shared__ float sA[2][64];
    __shared__ float sX[2][4];

    // ---- staging (once per block) ----
    {
        const uint4* s1 = (const uint4*)w2x;
        uint4* d1 = (uint4*)sw2;
        #pragma unroll
        for (int it = 0; it < 9; ++it) {
            const int idx = T + 256*it;
            if (idx < 128*PSTR/8) d1[idx] = s1[idx];
        }
        if (T < 128) w0s[T] = kvw1[T];
        if (T < 64)            knws[T]       = knw[T];
        else if (T < 128)      knbs[T - 64]  = knb[T - 64];
        else if (T < 192)      pxs[T - 128]  = pxw2[T - 128];
    }
    __syncthreads();

    const unsigned short* PtG = Ptb + (size_t)g*64*PSTR;
    const unsigned short* Gw  = w2x + 128*PSTR;     // G-weight rows (global)
    const float mflag = (m == 15) ? 1.0f : 0.0f;

    #pragma unroll 1
    for (int i = 0; i < 4; ++i) {
        const int dql = i*2 + pair;         // 0..7 local dst
        const int dl  = dgrp*8 + dql;       // 0..63 in-graph dst
        const int d   = g*64 + dl;

        // ---- Qn for this dst (global, L2-hot); issue early ----
        float qdv[4];
        #pragma unroll
        for (int ct = 0; ct < 4; ++ct)
            qdv[ct] = Qn[(size_t)d*64 + ct*16 + m];

        // ---- geometry for this wave's 32 src rows (Xn from global) ----
        if (L < 32) {
            const int row = half*32 + L;
            const float4 xs  = *(const float4*)&Xn4[(g*64 + row)*4];
            const float4 xdv = *(const float4*)&Xn4[(g*64 + dl)*4];
            const float r0 = xs.x - xdv.x, r1 = xs.y - xdv.y, r2 = xs.z - xdv.z;
            const float rd = r0*r0 + r1*r1 + r2*r2;
            const float inv = frcp(1.0f + sqrtf(rd + 1e-8f));
            float4 o; o.x = r0*inv; o.y = r1*inv; o.z = r2*inv; o.w = rd;
            *(float4*)&sxr[w][L][0] = o;
        }
        asm volatile("s_waitcnt lgkmcnt(0)" ::: "memory");

        // ---- build t A-fragments (rows half*32 + rt*16 + m) ----
        bf16x8 af[2][4];
        float rdv[2];
        #pragma unroll
        for (int rt = 0; rt < 2; ++rt) rdv[rt] = sxr[w][rt*16 + m][3];
        #pragma unroll
        for (int ks = 0; ks < 4; ++ks) {
            float w0v[8];
            *(float4*)&w0v[0] = *(const float4*)&w0s[ks*32 + q*8];
            *(float4*)&w0v[4] = *(const float4*)&w0s[ks*32 + q*8 + 4];
            #pragma unroll
            for (int rt = 0; rt < 2; ++rt) {
                const int row = half*32 + rt*16 + m;
                const bf16x8 pb = *(const bf16x8*)&PtG[(size_t)row*PSTR + ks*32 + q*8];
                bf16x8 o;
                #pragma unroll
                for (int j = 0; j < 8; ++j) {
                    const float pf = (float)pb[j];
                    o[j] = (__bf16)silu_f(fmaf(rdv[rt], w0v[j], pf));
                }
                af[rt][ks] = o;
            }
        }

        // ---- K-pass: incremental ct, LN stats accumulate ----
        float qdw[4], Sqdw = 0.f, Sqdb = 0.f;
        #pragma unroll
        for (int ct = 0; ct < 4; ++ct) {
            qdw[ct] = qdv[ct] * knws[ct*16 + m];
            Sqdw += qdw[ct];
            Sqdb += qdv[ct] * knbs[ct*16 + m];
        }
        Sqdw = row_sum16(Sqdw);
        Sqdb = row_sum16(Sqdb);

        float s1a[2][4], s2a[2][4], skqa[2][4];
        #pragma unroll
        for (int rt = 0; rt < 2; ++rt)
            #pragma unroll
            for (int r = 0; r < 4; ++r) { s1a[rt][r]=0.f; s2a[rt][r]=0.f; skqa[rt][r]=0.f; }

        #pragma unroll
        for (int ct = 0; ct < 4; ++ct) {
            f32x4 acc[2];
            acc[0] = (f32x4){0.f,0.f,0.f,0.f};
            acc[1] = (f32x4){0.f,0.f,0.f,0.f};
            #pragma unroll
            for (int ks = 0; ks < 4; ++ks) {
                const bf16x8 b = *(const bf16x8*)&sw2[(ct*16 + m)*PSTR + ks*32 + q*8];
                #pragma unroll
                for (int rt = 0; rt < 2; ++rt)
                    acc[rt] = __builtin_amdgcn_mfma_f32_16x16x32_bf16(
                                  af[rt][ks], b, acc[rt], 0, 0, 0);
            }
            #pragma unroll
            for (int rt = 0; rt < 2; ++rt)
                #pragma unroll
                for (int r = 0; r < 4; ++r) {
                    const float kv = acc[rt][r];
                    s1a[rt][r] += kv;
                    s2a[rt][r] = fmaf(kv, kv, s2a[rt][r]);
                    skqa[rt][r] = fmaf(kv, qdw[ct], skqa[rt][r]);
                }
        }

        float sc[2][4];
        #pragma unroll
        for (int rt = 0; rt < 2; ++rt)
            #pragma unroll
            for (int r = 0; r < 4; ++r) {
                const float s1 = row_sum16(s1a[rt][r]);
                const float s2 = row_sum16(s2a[rt][r]);
                const float skq = row_sum16(skqa[rt][r]);
                const float mu = s1 * (1.0f/64.0f);
                const float rstd = rsqrtf(s2 * (1.0f/64.0f) - mu*mu + 1e-5f);
                float scv = (rstd * (skq - mu*Sqdw) + Sqdb) * 0.125f;
                scv = bcast15(scv);
                const int row_g = half*32 + rt*16 + q*4 + r;
                sc[rt][r] = (row_g == dl) ? -1e30f : scv;
            }

        // ---- softmax: wave-local partial + cross-half rescale ----
        float mx = -1e30f;
        #pragma unroll
        for (int rt = 0; rt < 2; ++rt)
            #pragma unroll
            for (int r = 0; r < 4; ++r) mx = fmaxf(mx, sc[rt][r]);
        mx = fmaxf(mx, __shfl_xor(mx, 16, 64));
        mx = fmaxf(mx, __shfl_xor(mx, 32, 64));
        float al[2][4], S = 0.f;
        #pragma unroll
        for (int rt = 0; rt < 2; ++rt)
            #pragma unroll
            for (int r = 0; r < 4; ++r) {
                al[rt][r] = __expf(sc[rt][r] - mx);
                S += al[rt][r];
            }
        S += __shfl_xor(S, 16, 64);
        S += __shfl_xor(S, 32, 64);
        if (L == 0) { sred[pair][half][0] = mx; sred[pair][half][1] = S; }
        __syncthreads();                                    // b1
        {
            const float mo = sred[pair][half^1][0];
            const float So = sred[pair][half^1][1];
            const float M  = fmaxf(mx, mo);
            const float es = __expf(mx - M);
            const float eo = __expf(mo - M);
            const float alf = es * frcp(S*es + So*eo);
            #pragma unroll
            for (int rt = 0; rt < 2; ++rt)
                #pragma unroll
                for (int r = 0; r < 4; ++r) al[rt][r] *= alf;
        }

        // ---- V-pass: incremental ct ----
        float p[4];
        #pragma unroll
        for (int ct = 0; ct < 4; ++ct) {
            f32x4 acc[2];
            acc[0] = (f32x4){0.f,0.f,0.f,0.f};
            acc[1] = (f32x4){0.f,0.f,0.f,0.f};
            #pragma unroll
            for (int ks = 0; ks < 4; ++ks) {
                const bf16x8 b = *(const bf16x8*)&sw2[(64 + ct*16 + m)*PSTR + ks*32 + q*8];
                #pragma unroll
                for (int rt = 0; rt < 2; ++rt)
                    acc[rt] = __builtin_amdgcn_mfma_f32_16x16x32_bf16(
                                  af[rt][ks], b, acc[rt], 0, 0, 0);
            }
            float pv = 0.f;
            #pragma unroll
            for (int rt = 0; rt < 2; ++rt)
                #pragma unroll
                for (int r = 0; r < 4; ++r)
                    pv = fmaf(al[rt][r], acc[rt][r], pv);
            pv += __shfl_xor(pv, 16, 64);
            pv += __shfl_xor(pv, 32, 64);
            p[ct] = pv;
        }

        // ---- G-pass: incremental ct, phsum accumulate ----
        float phsum[2][4];
        #pragma unroll
        for (int rt = 0; rt < 2; ++rt)
            #pragma unroll
            for (int r = 0; r < 4; ++r) phsum[rt][r] = 0.f;
        #pragma unroll
        for (int ct = 0; ct < 4; ++ct) {
            f32x4 acc[2];
            acc[0] = (f32x4){0.f,0.f,0.f,0.f};
            acc[1] = (f32x4){0.f,0.f,0.f,0.f};
            #pragma unroll
            for (int ks = 0; ks < 4; ++ks) {
                const bf16x8 b = *(const bf16x8*)&Gw[(size_t)(ct*16 + m)*PSTR + ks*32 + q*8];
                #pragma unroll
                for (int rt = 0; rt < 2; ++rt)
                    acc[rt] = __builtin_amdgcn_mfma_f32_16x16x32_bf16(
                                  af[rt][ks], b, acc[rt], 0, 0, 0);
            }
            const float px = pxs[ct*16 + m];
            #pragma unroll
            for (int rt = 0; rt < 2; ++rt)
                #pragma unroll
                for (int r = 0; r < 4; ++r)
                    phsum[rt][r] = fmaf(silu_f(al[rt][r] * acc[rt][r]), px, phsum[rt][r]);
        }

        // ---- phx epilogue (DPP; valid at m==15) + X partial ----
        float xa0 = 0.f, xa1 = 0.f, xa2 = 0.f;
        #pragma unroll
        for (int rt = 0; rt < 2; ++rt)
            #pragma unroll
            for (int r = 0; r < 4; ++r) {
                const float ph = row_sum16(phsum[rt][r]) * mflag;
                const float4 xr = *(const float4*)&sxr[w][rt*16 + q*4 + r][0];
                xa0 = fmaf(ph, xr.x, xa0);
                xa1 = fmaf(ph, xr.y, xa1);
                xa2 = fmaf(ph, xr.z, xa2);
            }
        xa0 += __shfl_xor(xa0, 16, 64); xa0 += __shfl_xor(xa0, 32, 64);
        xa1 += __shfl_xor(xa1, 16, 64); xa1 += __shfl_xor(xa1, 32, 64);
        xa2 += __shfl_xor(xa2, 16, 64); xa2 += __shfl_xor(xa2, 32, 64);

        if (half == 1) {
            if (q == 0)
                #pragma unroll
                for (int ct = 0; ct < 4; ++ct) sA[pair][ct*16 + m] = p[ct];
            if (L == 15) {
                sX[pair][0] = xa0; sX[pair][1] = xa1; sX[pair][2] = xa2;
            }
        }
        __syncthreads();                                    // b2
        if (half == 0) {
            if (q == 0)
                #pragma unroll
                for (int ct = 0; ct < 4; ++ct)
                    sAb[dql*WS72 + ct*16 + m] =
                        bf16bits(p[ct] + sA[pair][ct*16 + m]);
            if (L == 15) {
                const float4 xdv = *(const float4*)&Xn4[(g*64 + dl)*4];
                Xout[(size_t)d*3 + 0] = xdv.x + xa0 + sX[pair][0];
                Xout[(size_t)d*3 + 1] = xdv.y + xa1 + sX[pair][1];
                Xout[(size_t)d*3 + 2] = xdv.z + xa2 + sX[pair][2];
            }
        }
    }

    // ---- fused k4: H_out MLP for this block's 8 dsts (wave 0 only) ----
    __syncthreads();
    if (w == 0) {
        const int mr = m & 7;
        const size_t nbase = (size_t)g*64 + dgrp*8;

        bf16x8 uf[2];
        #pragma unroll
        for (int ks = 0; ks < 2; ++ks) {
            const bf16x8 a8 = *(const bf16x8*)&sAb[mr*WS72 + ks*32 + q*8];
            float h[8], v[8];
            *(float4*)&h[0] = *(const float4*)&H[(nbase + mr)*64 + ks*32 + q*8];
            *(float4*)&h[4] = *(const float4*)&H[(nbase + mr)*64 + ks*32 + q*8 + 4];
            #pragma unroll
            for (int j = 0; j < 8; ++j) {
                const float a = (float)a8[j];
                v[j] = a * a * h[j];
            }
            uf[ks] = to_bf16x8(v);
        }

        f32x4 acc[4];
        #pragma unroll
        for (int ct = 0; ct < 4; ++ct) acc[ct] = (f32x4){0.f,0.f,0.f,0.f};
        #pragma unroll
        for (int ks = 0; ks < 2; ++ks)
            #pragma unroll
            for (int ct = 0; ct < 4; ++ct) {
                const bf16x8 b = *(const bf16x8*)&phhT[(ct*16 + m)*WS72 + ks*32 + q*8];
                acc[ct] = __builtin_amdgcn_mfma_f32_16x16x32_bf16(uf[ks], b, acc[ct], 0, 0, 0);
            }
        #pragma unroll
        for (int ct = 0; ct < 4; ++ct) {
            const float bv = phb1[ct*16 + m];
            #pragma unroll
            for (int r = 0; r < 4; ++r)
                if (q < 2)
                    sAb[(q*4 + r)*WS72 + ct*16 + m] = bf16bits(silu_f(acc[ct][r] + bv));
        }

        bf16x8 zf[2];
        #pragma unroll
        for (int ks = 0; ks < 2; ++ks)
            zf[ks] = *(const bf16x8*)&sAb[mr*WS72 + ks*32 + q*8];
        const unsigned short* phh2T = phhT + 64*WS72;
        #pragma unroll
        for (int ct = 0; ct < 4; ++ct) acc[ct] = (f32x4){0.f,0.f,0.f,0.f};
        #pragma unroll
        for (int ks = 0; ks < 2; ++ks)
            #pragma unroll
            for (int ct = 0; ct < 4; ++ct) {
                const bf16x8 b = *(const bf16x8*)&phh2T[(ct*16 + m)*WS72 + ks*32 + q*8];
                acc[ct] = __builtin_amdgcn_mfma_f32_16x16x32_bf16(zf[ks], b, acc[ct], 0, 0, 0);
            }
        #pragma unroll
        for (int ct = 0; ct < 4; ++ct) {
            const float bv = phb2[ct*16 + m];
            #pragma unroll
            for (int r = 0; r < 4; ++r)
                if (q < 2) {
                    const size_t idx = (nbase + q*4 + r)*64 + ct*16 + m;
                    Hout[idx] = H[idx] + acc[ct][r] + bv;
                }
        }
    }
}

// ---------------------------------------------------------------------------
extern "C" void kernel_launch(void* const* d_in, const int* in_sizes, int n_in,
                              void* d_out, int out_size, void* d_ws, size_t ws_size,
                              hipStream_t stream) {
    const float* X    = (const float*)d_in[1];
    const float* H    = (const float*)d_in[2];
    const float* xw   = (const float*)d_in[4];
    const float* qw1  = (const float*)d_in[5];
    const float* qw2  = (const float*)d_in[6];
    const float* kvw1 = (const float*)d_in[7];
    const float* kvw2 = (const float*)d_in[8];
    const float* qnw  = (const float*)d_in[9];
    const float* qnb  = (const float*)d_in[10];
    const float* knw  = (const float*)d_in[11];
    const float* knb  = (const float*)d_in[12];
    const float* pxw1 = (const float*)d_in[13];
    const float* pxw2 = (const float*)d_in[14];
    const float* phw1 = (const float*)d_in[15];
    const float* phb1 = (const float*)d_in[16];
    const float* phw2 = (const float*)d_in[17];
    const float* phb2 = (const float*)d_in[18];

    float* out = (float*)d_out;
    char*  ws  = (char*)d_ws;

    size_t off = 0;
    float* Xn4 = (float*)(ws + off);          off += (size_t)NTOT*4*4;
    float* Qn  = (float*)(ws + off);          off += (size_t)NTOT*64*4;
    unsigned short* Ptb = (unsigned short*)(ws + off); off += (size_t)NTOT*PSTR*2;
    unsigned short* w2x   = (unsigned short*)(ws + off); off += (size_t)192*PSTR*2;
    // k2 weights contiguous: qw1T | qw2T | kvw1T  (256 rows x WS72)
    unsigned short* qw1T  = (unsigned short*)(ws + off); off += (size_t)64*WS72*2;
    unsigned short* qw2T  = (unsigned short*)(ws + off); off += (size_t)64*WS72*2;
    unsigned short* kvw1T = (unsigned short*)(ws + off); off += (size_t)128*WS72*2;
    // k3 H-MLP weights contiguous: phh1T | phh2T  (128 rows x WS72)
    unsigned short* phh1T = (unsigned short*)(ws + off); off += (size_t)64*WS72*2;
    unsigned short* phh2T = (unsigned short*)(ws + off); off += (size_t)64*WS72*2;

    k0_prep<<<128, 256, 0, stream>>>(kvw2, pxw1, X, xw, qw1, qw2, kvw1,
                                     phw1, phw2, w2x, Xn4,
                                     qw1T, qw2T, kvw1T, phh1T, phh2T);
    k2_node<<<1024, 64, 0, stream>>>(H, qw1T, qnw, qnb, Qn, Ptb);
    k3_edge<<<1024, 256, 0, stream>>>(Xn4, Qn, Ptb, w2x, kvw1, knw, knb,
                                      pxw2, phh1T, phb1, phb2, H,
                                      out + NTOT*3, out);
}